// Round 6
// baseline (478.166 us; speedup 1.0000x reference)
//
#include <hip/hip_runtime.h>
#include <math.h>

#define N_NODES 20000
#define N_EDGES 320000

typedef __attribute__((ext_vector_type(8))) __bf16 bf16x8;
typedef __attribute__((ext_vector_type(8))) unsigned short ushort8;
typedef __attribute__((ext_vector_type(4))) float floatx4;

// ---- fp32 -> bf16 (RNE) raw bits ----
__device__ __forceinline__ unsigned short f2b(float f) {
    unsigned int u = __float_as_uint(f);
    unsigned int r = (u + 0x7fffu + ((u >> 16) & 1u)) >> 16;
    return (unsigned short)r;
}
// ---- bf16 bits -> fp32 ----
__device__ __forceinline__ float b2f(unsigned short u) {
    return __uint_as_float(((unsigned int)u) << 16);
}

// ---- merged prep: in_proj + dst-histogram + all weight converts (plain) ----
// ranges are multiples of 256 so each block is branch-uniform.
//   [0, 640000)          : h0[n][p] = x[n]@W_in + b_in  (bf16)
//   [640000, 960000)     : atomicAdd histogram of dst
//   [960000, 1500672)    : W[K][N] fp32 -> Wt[N][K] bf16 (W_cls padded to 1024 rows)
__global__ void k_prep(const float* __restrict__ x, const float* __restrict__ Wi,
                       const float* __restrict__ bi, unsigned short* __restrict__ h0,
                       const int* __restrict__ dst, int* __restrict__ cnt,
                       const float* __restrict__ Wl1, const float* __restrict__ Wr1,
                       const float* __restrict__ Wdn, const float* __restrict__ Wl2,
                       const float* __restrict__ Wr2, const float* __restrict__ Wup,
                       const float* __restrict__ Wcl,
                       unsigned short* __restrict__ o1, unsigned short* __restrict__ o2,
                       unsigned short* __restrict__ o3, unsigned short* __restrict__ o4,
                       unsigned short* __restrict__ o5, unsigned short* __restrict__ o6,
                       unsigned short* __restrict__ o7) {
    int t = blockIdx.x * blockDim.x + threadIdx.x;
    if (t < 640000) {
        int n = t >> 5, p = t & 31;
        float acc = bi[p];
        const float* xr = x + n * 18;
#pragma unroll
        for (int k = 0; k < 18; k++) acc = fmaf(xr[k], Wi[k * 32 + p], acc);
        h0[t] = f2b(acc);
        return;
    }
    if (t < 960000) {
        atomicAdd(cnt + dst[t - 640000], 1);
        return;
    }
    int u = t - 960000;
    const float* W; unsigned short* O; int Nd, K, idx;
    if (u < 8192)        { W = Wl1; O = o1; Nd = 256;  K = 32;  idx = u; }
    else if (u < 16384)  { W = Wr1; O = o2; Nd = 256;  K = 32;  idx = u - 8192; }
    else if (u < 81920)  { W = Wdn; O = o3; Nd = 256;  K = 256; idx = u - 16384; }
    else if (u < 147456) { W = Wl2; O = o4; Nd = 256;  K = 256; idx = u - 81920; }
    else if (u < 212992) { W = Wr2; O = o5; Nd = 256;  K = 256; idx = u - 147456; }
    else if (u < 278528) { W = Wup; O = o6; Nd = 256;  K = 256; idx = u - 212992; }
    else if (u < 540672) { W = Wcl; O = o7; Nd = 1000; K = 256; idx = u - 278528; }
    else return;
    int n = idx / K, k = idx % K;
    float v = (n < Nd) ? W[(size_t)k * Nd + n] : 0.f;   // pad rows -> 0
    O[idx] = f2b(v);
}

// ---- bf16 MFMA GEMM (generic, LDS-staged): C[M,N] = A[M,K] @ Bt[N,K]^T
// kept only for the K=32 in-proj GEMM.
__global__ __launch_bounds__(256) void k_gemm_bf16(
    const unsigned short* __restrict__ A, const unsigned short* __restrict__ Bt,
    float* __restrict__ Cf, unsigned short* __restrict__ Cb,
    const float* __restrict__ bias, int M, int N, int K) {
    __shared__ unsigned short As[8 * 64 * 8];
    __shared__ unsigned short Bs[8 * 64 * 8];
    int tid = threadIdx.x;
    int wave = tid >> 6, lane = tid & 63;
    int wr = wave >> 1, wc = wave & 1;
    int row0 = blockIdx.x * 128, col0 = blockIdx.y * 128;
    floatx4 zero4 = {0.f, 0.f, 0.f, 0.f};
    floatx4 acc[4][4];
#pragma unroll
    for (int i = 0; i < 4; i++)
#pragma unroll
        for (int j = 0; j < 4; j++) acc[i][j] = zero4;
    for (int kb = 0; kb < K; kb += 32) {
#pragma unroll
        for (int q = 0; q < 2; q++) {
            int c = tid * 2 + q;           // 0..511
            int row = c >> 2, koff = (c & 3) * 8;
            int lp = (row & 15) + 16 * (koff >> 3);
            int mt = row >> 4;
            ushort8 va = {0, 0, 0, 0, 0, 0, 0, 0};
            if (row0 + row < M)
                va = *(const ushort8*)(A + (size_t)(row0 + row) * K + kb + koff);
            *(ushort8*)(As + (mt * 64 + lp) * 8) = va;
            ushort8 vb = {0, 0, 0, 0, 0, 0, 0, 0};
            if (col0 + row < N)
                vb = *(const ushort8*)(Bt + (size_t)(col0 + row) * K + kb + koff);
            *(ushort8*)(Bs + (mt * 64 + lp) * 8) = vb;
        }
        __syncthreads();
        bf16x8 af[4], bfr[4];
#pragma unroll
        for (int i = 0; i < 4; i++)
            af[i] = *(const bf16x8*)(As + ((wr * 4 + i) * 64 + lane) * 8);
#pragma unroll
        for (int j = 0; j < 4; j++)
            bfr[j] = *(const bf16x8*)(Bs + ((wc * 4 + j) * 64 + lane) * 8);
#pragma unroll
        for (int i = 0; i < 4; i++)
#pragma unroll
            for (int j = 0; j < 4; j++)
                acc[i][j] = __builtin_amdgcn_mfma_f32_16x16x32_bf16(
                    af[i], bfr[j], acc[i][j], 0, 0, 0);
        __syncthreads();
    }
    int quad = lane >> 4, nl = lane & 15;
#pragma unroll
    for (int i = 0; i < 4; i++) {
#pragma unroll
        for (int j = 0; j < 4; j++) {
            int col = col0 + wc * 64 + j * 16 + nl;
            if (col >= N) continue;
            float bv = bias ? bias[col] : 0.f;
#pragma unroll
            for (int r = 0; r < 4; r++) {
                int rr = row0 + wr * 64 + i * 16 + quad * 4 + r;
                if (rr >= M) continue;
                float v = acc[i][j][r] + bv;
                if (Cf) Cf[(size_t)rr * N + col] = v;
                else Cb[(size_t)rr * N + col] = f2b(v);
            }
        }
    }
}

// ---- K=256 GEMM, B in REGISTERS (no LDS panel) + optional fused LayerNorm ----
// Round-5 post-mortem: the 128 KB LDS B-panel forced 1 block/CU and exposed the
// whole stage->sync->compute chain. Here: 512 threads = 8 col-waves x 32 cols
// (block = 16 rows x 256 cols, M = 20000 = 1250 x 16, guard-free rows).
// Each wave holds its OWN 32-col x 256-K B slice in 64 VGPRs (no redundancy);
// the 16x256 A strip is staged once through 8 KB of chunk-XOR-swizzled LDS and
// shared by all 8 waves. ~100 VGPR -> 4 waves/SIMD, 2 blocks/CU co-resident.
// One barrier per block; 16 MFMAs per wave from registers.
__global__ __launch_bounds__(512) void k_gemm_reg(
    const unsigned short* __restrict__ A,    // [M][256] bf16
    const unsigned short* __restrict__ Bt,   // [Npad][256] bf16 (plain)
    int Ncols, int ldC,
    const float* __restrict__ bias,          // per-col bias or null
    const float* __restrict__ res,           // [M][256] fp32 residual (LN only) or null
    const float* __restrict__ g, const float* __restrict__ b,  // LN params or null
    float* __restrict__ outf, unsigned short* __restrict__ outb) {
    __shared__ unsigned short As[16 * 256];  // 8 KB A strip, chunk-swizzled
    __shared__ float red[8][16][2];          // per-col-wave (sum,sumsq) per row
    int tid = threadIdx.x, lane = tid & 63, wave = tid >> 6;
    int nl = lane & 15, quad = lane >> 4;
    int row0 = blockIdx.x * 16;
    int cbase = blockIdx.y * 256 + wave * 32;

    // stage A strip: thread (r = tid>>5, c = tid&31) copies one 16B chunk,
    // writing to chunk' = c ^ (r&7) so the per-(nl,quad) read is ~conflict-free.
    {
        int r = tid >> 5, c = tid & 31;
        ushort8 v = *(const ushort8*)(A + (size_t)(row0 + r) * 256 + c * 8);
        *(ushort8*)(As + r * 256 + ((c ^ (r & 7)) << 3)) = v;
    }
    // B slice -> registers (each wave owns 32 distinct cols)
    bf16x8 breg[2][8];
    const unsigned short* bptr = Bt + (size_t)(cbase + nl) * 256 + quad * 8;
#pragma unroll
    for (int j = 0; j < 2; j++)
#pragma unroll
        for (int kb = 0; kb < 8; kb++)
            breg[j][kb] = *(const bf16x8*)(bptr + j * 16 * 256 + kb * 32);
    __syncthreads();

    floatx4 zero4 = {0.f, 0.f, 0.f, 0.f};
    floatx4 acc[2];
    acc[0] = zero4; acc[1] = zero4;
#pragma unroll
    for (int kb = 0; kb < 8; kb++) {
        int kq = kb * 4 + quad;
        bf16x8 a = *(const bf16x8*)(As + nl * 256 + (((kq ^ (nl & 7))) << 3));
        acc[0] = __builtin_amdgcn_mfma_f32_16x16x32_bf16(a, breg[0][kb], acc[0], 0, 0, 0);
        acc[1] = __builtin_amdgcn_mfma_f32_16x16x32_bf16(a, breg[1][kb], acc[1], 0, 0, 0);
    }

    if (g == nullptr) {
        // plain epilogue: optional bias, col-guarded stores (rows exact)
#pragma unroll
        for (int j = 0; j < 2; j++) {
            int col = cbase + j * 16 + nl;
            if (col >= Ncols) continue;
            float bv = bias ? bias[col] : 0.f;
#pragma unroll
            for (int r = 0; r < 4; r++) {
                int rr = row0 + quad * 4 + r;
                float v = acc[j][r] + bv;
                if (outf) outf[(size_t)rr * ldC + col] = v;
                if (outb) outb[(size_t)rr * ldC + col] = f2b(v);
            }
        }
        return;
    }

    // ---- fused LayerNorm epilogue (Ncols == 256, ldC == 256, blockIdx.y == 0) ----
    if (res) {
#pragma unroll
        for (int j = 0; j < 2; j++) {
            int col = cbase + j * 16 + nl;
#pragma unroll
            for (int r = 0; r < 4; r++)
                acc[j][r] += res[(size_t)(row0 + quad * 4 + r) * 256 + col];
        }
    }
    // per-wave partials over its 32 cols; rows live in 16-lane (same-quad) groups
#pragma unroll
    for (int r = 0; r < 4; r++) {
        float s = acc[0][r] + acc[1][r];
        float q = fmaf(acc[0][r], acc[0][r], acc[1][r] * acc[1][r]);
        s += __shfl_xor(s, 1, 64); q += __shfl_xor(q, 1, 64);
        s += __shfl_xor(s, 2, 64); q += __shfl_xor(q, 2, 64);
        s += __shfl_xor(s, 4, 64); q += __shfl_xor(q, 4, 64);
        s += __shfl_xor(s, 8, 64); q += __shfl_xor(q, 8, 64);
        if (nl == 0) {
            red[wave][quad * 4 + r][0] = s;
            red[wave][quad * 4 + r][1] = q;
        }
    }
    __syncthreads();
    float mean_[4], rstd_[4];
#pragma unroll
    for (int r = 0; r < 4; r++) {
        int row = quad * 4 + r;
        float s = 0.f, q = 0.f;
#pragma unroll
        for (int w = 0; w < 8; w++) { s += red[w][row][0]; q += red[w][row][1]; }
        float mean = s * (1.0f / 256.0f);
        float var = q * (1.0f / 256.0f) - mean * mean;
        mean_[r] = mean;
        rstd_[r] = 1.0f / sqrtf(var + 1e-5f);
    }
#pragma unroll
    for (int j = 0; j < 2; j++) {
        int col = cbase + j * 16 + nl;
        float gv = g[col], bvv = b[col];
#pragma unroll
        for (int r = 0; r < 4; r++) {
            int rr = row0 + quad * 4 + r;
            float o = (acc[j][r] - mean_[r]) * rstd_[r] * gv + bvv;
            if (outf) outf[(size_t)rr * 256 + col] = o;
            if (outb) outb[(size_t)rr * 256 + col] = f2b(o);
        }
    }
}

// ---- CSR build: fast single-block scan (1024 threads, 20 elems/thread) ----
__global__ __launch_bounds__(1024) void k_scan(const int* __restrict__ cnt,
                                               int* __restrict__ rowptr,
                                               int* __restrict__ wp, int n) {
    __shared__ int tsum[1024];
    int t = threadIdx.x;
    const int chunk = 20;  // 1024*20 = 20480 >= 20000
    int i0 = t * chunk;
    int local[chunk];
    int s = 0;
#pragma unroll
    for (int j = 0; j < chunk; j++) {
        int i = i0 + j;
        int v = (i < n) ? cnt[i] : 0;
        local[j] = s;  // exclusive prefix within chunk
        s += v;
    }
    tsum[t] = s;
    __syncthreads();
    // inclusive Hillis-Steele scan over 1024 partials
    for (int off = 1; off < 1024; off <<= 1) {
        int other = (t >= off) ? tsum[t - off] : 0;
        __syncthreads();
        tsum[t] += other;
        __syncthreads();
    }
    int base = (t > 0) ? tsum[t - 1] : 0;
#pragma unroll
    for (int j = 0; j < chunk; j++) {
        int i = i0 + j;
        if (i < n) {
            int ex = base + local[j];
            rowptr[i] = ex;
            wp[i] = ex;
        }
    }
    if (t == 1023) rowptr[n] = tsum[1023];
}

// ---- CSR build: scatter src id + edge attr into CSR order ----
__global__ void k_fill(const int* __restrict__ src, const int* __restrict__ dst,
                       const float* __restrict__ ea, int* __restrict__ wp,
                       int* __restrict__ srcs, float* __restrict__ eas) {
    int e = blockIdx.x * blockDim.x + threadIdx.x;
    if (e >= N_EDGES) return;
    int p = atomicAdd(wp + dst[e], 1);
    srcs[p] = src[e];
    eas[p] = ea[e];
}

// ---- fused GATv2 edge phase + LayerNorm epilogue
// wave per dst node, online softmax, 2 edges/iteration.
// Edge metadata (srcs/eas) is CSR-ordered -> sequential loads, no indirection.
// Row gathers are kept 3 pairs (6 edges) in flight to cover LLC/HBM latency.
// xlr: [N][512] bf16 where cols 0..255 = x@Wl, 256..511 = x@Wr
// epilogue: o = agg + vbias (+res) ; LN(o; g,b) -> outf (fp32) / outb (bf16)
__global__ __launch_bounds__(256) void k_gat_ln(
    const int* __restrict__ rowptr, const int* __restrict__ srcs,
    const float* __restrict__ eas, const unsigned short* __restrict__ xlr,
    const float* __restrict__ We, const float* __restrict__ att,
    const float* __restrict__ vbias, const float* __restrict__ res,
    const float* __restrict__ g, const float* __restrict__ b,
    float* __restrict__ outf, unsigned short* __restrict__ outb) {
    int node = blockIdx.x * 4 + (threadIdx.x >> 6);
    if (node >= N_NODES) return;
    int lane = threadIdx.x & 63;  // lane covers dims [4*lane, 4*lane+4)
    int beg = rowptr[node], end = rowptr[node + 1];
    float4 wv = ((const float4*)We)[lane];
    float4 av = ((const float4*)att)[lane];
    ushort4 xru = ((const ushort4*)(xlr + (size_t)node * 512 + 256))[lane];
    float4 rv = make_float4(b2f(xru.x), b2f(xru.y), b2f(xru.z), b2f(xru.w));
    float m = -3.0e38f, l = 0.f;
    float4 acc = make_float4(0.f, 0.f, 0.f, 0.f);
    if (beg < end) {
        int last = end - 1;
        int i1 = (beg + 1 < end) ? beg + 1 : last;
        int i2 = (beg + 2 < end) ? beg + 2 : last;
        int i3 = (beg + 3 < end) ? beg + 3 : last;
        int i4 = (beg + 4 < end) ? beg + 4 : last;
        int i5 = (beg + 5 < end) ? beg + 5 : last;
        int i6 = (beg + 6 < end) ? beg + 6 : last;
        int i7 = (beg + 7 < end) ? beg + 7 : last;
        int s0a = srcs[beg], s0b = srcs[i1];
        int s1a = srcs[i2],  s1b = srcs[i3];
        int s2a = srcs[i4],  s2b = srcs[i5];
        int s3a = srcs[i6],  s3b = srcs[i7];
        float a0a = eas[beg], a0b = eas[i1];
        float a1a = eas[i2],  a1b = eas[i3];
        float a2a = eas[i4],  a2b = eas[i5];
        float a3a = eas[i6],  a3b = eas[i7];
        ushort4 x0a = ((const ushort4*)(xlr + (size_t)s0a * 512))[lane];
        ushort4 x0b = ((const ushort4*)(xlr + (size_t)s0b * 512))[lane];
        ushort4 x1a = ((const ushort4*)(xlr + (size_t)s1a * 512))[lane];
        ushort4 x1b = ((const ushort4*)(xlr + (size_t)s1b * 512))[lane];
        ushort4 x2a = ((const ushort4*)(xlr + (size_t)s2a * 512))[lane];
        ushort4 x2b = ((const ushort4*)(xlr + (size_t)s2b * 512))[lane];
        for (int i = beg; i < end; i += 2) {
            int j8 = (i + 8 < end) ? i + 8 : last;
            int j9 = (i + 9 < end) ? i + 9 : last;
            int s4a = srcs[j8], s4b = srcs[j9];
            float a4a = eas[j8], a4b = eas[j9];
            ushort4 x3a = ((const ushort4*)(xlr + (size_t)s3a * 512))[lane];
            ushort4 x3b = ((const ushort4*)(xlr + (size_t)s3b * 512))[lane];
            float4 lva = make_float4(b2f(x0a.x), b2f(x0a.y), b2f(x0a.z), b2f(x0a.w));
            float4 lvb = make_float4(b2f(x0b.x), b2f(x0b.y), b2f(x0b.z), b2f(x0b.w));
            float f, pa = 0.f, pb = 0.f;
            f = lva.x + rv.x + a0a * wv.x; f = fmaxf(f, 0.2f * f); pa = fmaf(f, av.x, pa);
            f = lva.y + rv.y + a0a * wv.y; f = fmaxf(f, 0.2f * f); pa = fmaf(f, av.y, pa);
            f = lva.z + rv.z + a0a * wv.z; f = fmaxf(f, 0.2f * f); pa = fmaf(f, av.z, pa);
            f = lva.w + rv.w + a0a * wv.w; f = fmaxf(f, 0.2f * f); pa = fmaf(f, av.w, pa);
            f = lvb.x + rv.x + a0b * wv.x; f = fmaxf(f, 0.2f * f); pb = fmaf(f, av.x, pb);
            f = lvb.y + rv.y + a0b * wv.y; f = fmaxf(f, 0.2f * f); pb = fmaf(f, av.y, pb);
            f = lvb.z + rv.z + a0b * wv.z; f = fmaxf(f, 0.2f * f); pb = fmaf(f, av.z, pb);
            f = lvb.w + rv.w + a0b * wv.w; f = fmaxf(f, 0.2f * f); pb = fmaf(f, av.w, pb);
            pa += __shfl_xor(pa, 1, 64);
            pa += __shfl_xor(pa, 2, 64);
            pa += __shfl_xor(pa, 4, 64);
            pb += __shfl_xor(pb, 1, 64);
            pb += __shfl_xor(pb, 2, 64);
            pb += __shfl_xor(pb, 4, 64);
            if (i + 1 >= end) pb = -3.0e38f;  // odd tail: second edge is a dummy
            float mnew = fmaxf(fmaxf(m, pa), pb);
            float scale = __expf(m - mnew);
            float wa = __expf(pa - mnew);
            float wb = __expf(pb - mnew);
            acc.x = fmaf(acc.x, scale, fmaf(wa, lva.x, wb * lvb.x));
            acc.y = fmaf(acc.y, scale, fmaf(wa, lva.y, wb * lvb.y));
            acc.z = fmaf(acc.z, scale, fmaf(wa, lva.z, wb * lvb.z));
            acc.w = fmaf(acc.w, scale, fmaf(wa, lva.w, wb * lvb.w));
            l = fmaf(l, scale, wa + wb);
            m = mnew;
            x0a = x1a; x0b = x1b; x1a = x2a; x1b = x2b; x2a = x3a; x2b = x3b;
            a0a = a1a; a0b = a1b; a1a = a2a; a1b = a2b; a2a = a3a; a2b = a3b;
            a3a = a4a; a3b = a4b; s3a = s4a; s3b = s4b;
        }
    }
    float inv = 1.0f / (l + 1e-16f);
    float4 vb4 = ((const float4*)vbias)[lane];
    float4 o = make_float4(fmaf(acc.x, inv, vb4.x), fmaf(acc.y, inv, vb4.y),
                           fmaf(acc.z, inv, vb4.z), fmaf(acc.w, inv, vb4.w));
    if (res) {
        float4 r4 = ((const float4*)(res + (size_t)node * 256))[lane];
        o.x += r4.x; o.y += r4.y; o.z += r4.z; o.w += r4.w;
    }
    float sum = o.x + o.y + o.z + o.w;
#pragma unroll
    for (int off = 32; off > 0; off >>= 1) sum += __shfl_xor(sum, off, 64);
    float mean = sum * (1.0f / 256.0f);
    float dx = o.x - mean, dy = o.y - mean, dz = o.z - mean, dw = o.w - mean;
    float sq = dx * dx + dy * dy + dz * dz + dw * dw;
#pragma unroll
    for (int off = 32; off > 0; off >>= 1) sq += __shfl_xor(sq, off, 64);
    float rstd = 1.0f / sqrtf(sq * (1.0f / 256.0f) + 1e-5f);
    float4 gg = ((const float4*)g)[lane];
    float4 bb = ((const float4*)b)[lane];
    float4 o4 = make_float4(dx * rstd * gg.x + bb.x, dy * rstd * gg.y + bb.y,
                            dz * rstd * gg.z + bb.z, dw * rstd * gg.w + bb.w);
    if (outf) ((float4*)(outf + (size_t)node * 256))[lane] = o4;
    if (outb) {
        ushort4 u;
        u.x = f2b(o4.x); u.y = f2b(o4.y); u.z = f2b(o4.z); u.w = f2b(o4.w);
        ((ushort4*)(outb + (size_t)node * 256))[lane] = u;
    }
}

extern "C" void kernel_launch(void* const* d_in, const int* in_sizes, int n_in,
                              void* d_out, int out_size, void* d_ws, size_t ws_size,
                              hipStream_t stream) {
    const float* x_gnn = (const float*)d_in[0];
    const int* ei = (const int*)d_in[1];
    const int* src = ei;
    const int* dst = ei + N_EDGES;
    const float* ea   = (const float*)d_in[2];
    const float* W_in = (const float*)d_in[3];
    const float* b_in = (const float*)d_in[4];
    const float* Wl1  = (const float*)d_in[5];
    const float* Wr1  = (const float*)d_in[6];
    const float* We1  = (const float*)d_in[7];
    const float* att1 = (const float*)d_in[8];
    const float* bg1  = (const float*)d_in[9];
    const float* ln1_g = (const float*)d_in[10];
    const float* ln1_b = (const float*)d_in[11];
    const float* W_down = (const float*)d_in[12];
    const float* lnd_g = (const float*)d_in[13];
    const float* lnd_b = (const float*)d_in[14];
    const float* Wl2  = (const float*)d_in[15];
    const float* Wr2  = (const float*)d_in[16];
    const float* We2  = (const float*)d_in[17];
    const float* att2 = (const float*)d_in[18];
    const float* bg2  = (const float*)d_in[19];
    const float* ln2_g = (const float*)d_in[20];
    const float* ln2_b = (const float*)d_in[21];
    const float* W_up = (const float*)d_in[22];
    const float* lnu_g = (const float*)d_in[23];
    const float* lnu_b = (const float*)d_in[24];
    const float* W_cls = (const float*)d_in[25];
    const float* b_cls = (const float*)d_in[26];

    // ---- workspace layout ----
    float* ws = (float*)d_ws;
    float* B_agg = ws;                                // 5,120,000 f (unused, kept for layout)
    float* B_h1  = B_agg + 5120000;                   // 5,120,000 f
    float* B_z   = B_h1 + 5120000;                    // 5,120,000 f
    unsigned short* B_xlr = (unsigned short*)(B_z + 5120000);  // 10,240,000 us ([N][512])
    unsigned short* B_actb = B_xlr + 10240000;                 // 5,120,000 us
    unsigned short* B_h0b = B_actb + 5120000;                  // 640,000 us
    unsigned short* Wt_l1 = B_h0b + 640000;                    // 8,192  ([512][32] with Wt_r1)
    unsigned short* Wt_r1 = Wt_l1 + 8192;                      // 8,192
    unsigned short* Wt_down = Wt_r1 + 8192;                    // 65,536 (plain [256][256])
    unsigned short* Wt_l2 = Wt_down + 65536;                   // ([512][256] with Wt_r2)
    unsigned short* Wt_r2 = Wt_l2 + 65536;
    unsigned short* Wt_up = Wt_r2 + 65536;                     // 65,536
    unsigned short* Wt_cls = Wt_up + 65536;                    // 262,144 ([1024][256], pad)
    int* C_cnt = (int*)(Wt_cls + 262144);                      // 20,000
    int* C_row = C_cnt + 20000;                                // 20,001
    int* C_wp  = C_row + 20001;                                // 20,000
    int* C_src = C_wp + 20000;                                 // 320,000 (CSR-ordered src)
    float* C_ea = (float*)(C_src + 320000);                    // 320,000 (CSR-ordered ea)

    float* out_logits = (float*)d_out;
    float* out_h = out_logits + (size_t)N_NODES * 1000;

    int gatblk = (N_NODES + 3) / 4;
    int gemmM16 = N_NODES / 16;          // 1250 exact (16-row tiles, guard-free)
    dim3 gl((N_NODES + 127) / 128, 4);   // K=32 gemm, N=512 (merged xl|xr)

    // 0. prep (in_proj + dst histogram + weight converts) — one launch
    hipMemsetAsync(C_cnt, 0, (size_t)20000 * 4, stream);
    k_prep<<<5862, 256, 0, stream>>>(x_gnn, W_in, b_in, B_h0b, dst, C_cnt,
                                     Wl1, Wr1, W_down, Wl2, Wr2, W_up, W_cls,
                                     Wt_l1, Wt_r1, Wt_down, Wt_l2, Wt_r2, Wt_up, Wt_cls);
    // 0b. CSR over dst (reused by both GAT layers)
    k_scan<<<1, 1024, 0, stream>>>(C_cnt, C_row, C_wp, N_NODES);
    k_fill<<<(N_EDGES + 255) / 256, 256, 0, stream>>>(src, dst, ea, C_wp, C_src, C_ea);

    // 1. merged xl|xr = h0 @ [Wl1|Wr1]  (N=512, K=32 MFMA, bf16 out)
    k_gemm_bf16<<<gl, 256, 0, stream>>>(B_h0b, Wt_l1, nullptr, B_xlr, nullptr, N_NODES, 512, 32);
    // 2. GAT1 fused (+bias +LN) -> h1 (fp32 for residual) + bf16 act
    k_gat_ln<<<gatblk, 256, 0, stream>>>(C_row, C_src, C_ea, B_xlr, We1, att1,
                                         bg1, nullptr, ln1_g, ln1_b, B_h1, B_actb);
    // 3. z = LN(h1 @ W_down)  (reg-B GEMM, fused LN, in-place row-safe)
    k_gemm_reg<<<dim3(gemmM16, 1), 512, 0, stream>>>(
        B_actb, Wt_down, 256, 256, nullptr, nullptr, lnd_g, lnd_b, B_z, B_actb);
    // 4. merged xl2|xr2 = z @ [Wl2|Wr2] (N=512)
    k_gemm_reg<<<dim3(gemmM16, 2), 512, 0, stream>>>(
        B_actb, Wt_l2, 512, 512, nullptr, nullptr, nullptr, nullptr, nullptr, B_xlr);
    // 5. GAT2 fused (+bias +residual z +LN) -> bf16 act
    k_gat_ln<<<gatblk, 256, 0, stream>>>(C_row, C_src, C_ea, B_xlr, We2, att2,
                                         bg2, B_z, ln2_g, ln2_b, nullptr, B_actb);
    // 6. h = LN(z2 @ W_up + h1) -> out_h (fp32) + bf16 act
    k_gemm_reg<<<dim3(gemmM16, 1), 512, 0, stream>>>(
        B_actb, Wt_up, 256, 256, nullptr, B_h1, lnu_g, lnu_b, out_h, B_actb);
    // 7. logits = h @ W_cls + b_cls  (N=1000, padded B image to 1024)
    k_gemm_reg<<<dim3(gemmM16, 4), 512, 0, stream>>>(
        B_actb, Wt_cls, 1000, 1000, b_cls, nullptr, nullptr, nullptr,
        out_logits, nullptr);
}

// Round 7
// 402.410 us; speedup vs baseline: 1.1883x; 1.1883x over previous
//
#include <hip/hip_runtime.h>
#include <math.h>

#define N_NODES 20000
#define N_EDGES 320000

typedef __attribute__((ext_vector_type(8))) __bf16 bf16x8;
typedef __attribute__((ext_vector_type(8))) unsigned short ushort8;
typedef __attribute__((ext_vector_type(4))) float floatx4;

// ---- fp32 -> bf16 (RNE) raw bits ----
__device__ __forceinline__ unsigned short f2b(float f) {
    unsigned int u = __float_as_uint(f);
    unsigned int r = (u + 0x7fffu + ((u >> 16) & 1u)) >> 16;
    return (unsigned short)r;
}
// ---- bf16 bits -> fp32 ----
__device__ __forceinline__ float b2f(unsigned short u) {
    return __uint_as_float(((unsigned int)u) << 16);
}

// ---- merged prep: in_proj + dst-histogram + all weight converts (plain) ----
//   [0, 640000)          : h0[n][p] = x[n]@W_in + b_in  (bf16)
//   [640000, 960000)     : atomicAdd histogram of dst
//   [960000, 1500672)    : W[K][N] fp32 -> Wt[N][K] bf16 (W_cls padded to 1024 rows)
__global__ void k_prep(const float* __restrict__ x, const float* __restrict__ Wi,
                       const float* __restrict__ bi, unsigned short* __restrict__ h0,
                       const int* __restrict__ dst, int* __restrict__ cnt,
                       const float* __restrict__ Wl1, const float* __restrict__ Wr1,
                       const float* __restrict__ Wdn, const float* __restrict__ Wl2,
                       const float* __restrict__ Wr2, const float* __restrict__ Wup,
                       const float* __restrict__ Wcl,
                       unsigned short* __restrict__ o1, unsigned short* __restrict__ o2,
                       unsigned short* __restrict__ o3, unsigned short* __restrict__ o4,
                       unsigned short* __restrict__ o5, unsigned short* __restrict__ o6,
                       unsigned short* __restrict__ o7) {
    int t = blockIdx.x * blockDim.x + threadIdx.x;
    if (t < 640000) {
        int n = t >> 5, p = t & 31;
        float acc = bi[p];
        const float* xr = x + n * 18;
#pragma unroll
        for (int k = 0; k < 18; k++) acc = fmaf(xr[k], Wi[k * 32 + p], acc);
        h0[t] = f2b(acc);
        return;
    }
    if (t < 960000) {
        atomicAdd(cnt + dst[t - 640000], 1);
        return;
    }
    int u = t - 960000;
    const float* W; unsigned short* O; int Nd, K, idx;
    if (u < 8192)        { W = Wl1; O = o1; Nd = 256;  K = 32;  idx = u; }
    else if (u < 16384)  { W = Wr1; O = o2; Nd = 256;  K = 32;  idx = u - 8192; }
    else if (u < 81920)  { W = Wdn; O = o3; Nd = 256;  K = 256; idx = u - 16384; }
    else if (u < 147456) { W = Wl2; O = o4; Nd = 256;  K = 256; idx = u - 81920; }
    else if (u < 212992) { W = Wr2; O = o5; Nd = 256;  K = 256; idx = u - 147456; }
    else if (u < 278528) { W = Wup; O = o6; Nd = 256;  K = 256; idx = u - 212992; }
    else if (u < 540672) { W = Wcl; O = o7; Nd = 1000; K = 256; idx = u - 278528; }
    else return;
    int n = idx / K, k = idx % K;
    float v = (n < Nd) ? W[(size_t)k * Nd + n] : 0.f;   // pad rows -> 0
    O[idx] = f2b(v);
}

// ---- bf16 MFMA GEMM (generic, LDS-staged): C[M,N] = A[M,K] @ Bt[N,K]^T
// kept only for the K=32 in-proj GEMM.
__global__ __launch_bounds__(256) void k_gemm_bf16(
    const unsigned short* __restrict__ A, const unsigned short* __restrict__ Bt,
    float* __restrict__ Cf, unsigned short* __restrict__ Cb,
    const float* __restrict__ bias, int M, int N, int K) {
    __shared__ unsigned short As[8 * 64 * 8];
    __shared__ unsigned short Bs[8 * 64 * 8];
    int tid = threadIdx.x;
    int wave = tid >> 6, lane = tid & 63;
    int wr = wave >> 1, wc = wave & 1;
    int row0 = blockIdx.x * 128, col0 = blockIdx.y * 128;
    floatx4 zero4 = {0.f, 0.f, 0.f, 0.f};
    floatx4 acc[4][4];
#pragma unroll
    for (int i = 0; i < 4; i++)
#pragma unroll
        for (int j = 0; j < 4; j++) acc[i][j] = zero4;
    for (int kb = 0; kb < K; kb += 32) {
#pragma unroll
        for (int q = 0; q < 2; q++) {
            int c = tid * 2 + q;           // 0..511
            int row = c >> 2, koff = (c & 3) * 8;
            int lp = (row & 15) + 16 * (koff >> 3);
            int mt = row >> 4;
            ushort8 va = {0, 0, 0, 0, 0, 0, 0, 0};
            if (row0 + row < M)
                va = *(const ushort8*)(A + (size_t)(row0 + row) * K + kb + koff);
            *(ushort8*)(As + (mt * 64 + lp) * 8) = va;
            ushort8 vb = {0, 0, 0, 0, 0, 0, 0, 0};
            if (col0 + row < N)
                vb = *(const ushort8*)(Bt + (size_t)(col0 + row) * K + kb + koff);
            *(ushort8*)(Bs + (mt * 64 + lp) * 8) = vb;
        }
        __syncthreads();
        bf16x8 af[4], bfr[4];
#pragma unroll
        for (int i = 0; i < 4; i++)
            af[i] = *(const bf16x8*)(As + ((wr * 4 + i) * 64 + lane) * 8);
#pragma unroll
        for (int j = 0; j < 4; j++)
            bfr[j] = *(const bf16x8*)(Bs + ((wc * 4 + j) * 64 + lane) * 8);
#pragma unroll
        for (int i = 0; i < 4; i++)
#pragma unroll
            for (int j = 0; j < 4; j++)
                acc[i][j] = __builtin_amdgcn_mfma_f32_16x16x32_bf16(
                    af[i], bfr[j], acc[i][j], 0, 0, 0);
        __syncthreads();
    }
    int quad = lane >> 4, nl = lane & 15;
#pragma unroll
    for (int i = 0; i < 4; i++) {
#pragma unroll
        for (int j = 0; j < 4; j++) {
            int col = col0 + wc * 64 + j * 16 + nl;
            if (col >= N) continue;
            float bv = bias ? bias[col] : 0.f;
#pragma unroll
            for (int r = 0; r < 4; r++) {
                int rr = row0 + wr * 64 + i * 16 + quad * 4 + r;
                if (rr >= M) continue;
                float v = acc[i][j][r] + bv;
                if (Cf) Cf[(size_t)rr * N + col] = v;
                else Cb[(size_t)rr * N + col] = f2b(v);
            }
        }
    }
}

// ---- K=256 GEMM: B in registers, grid-stride row strips, LDS-dbuf A ----
// Round-6 post-mortem: 16-row blocks re-fetched the 128 KB B-slice per block
// (640 MB L2 traffic for the cls GEMM) -> latency/L2-BW bound at 4% MfmaUtil.
// Here each block loads its B slice ONCE into registers (breg[2][8], 32
// cols/wave, layout verified in round 6) and loops row strips s = bIdx.x,
// s += gridDim.x. Per strip: issue next A-strip global load early (reg),
// compute current strip from LDS, store C, ds_write next strip, one barrier.
// B traffic = #blocks * 128 KB (64 MB cls), A strips read exactly once.
__global__ __launch_bounds__(512) void k_gemm_stride(
    const unsigned short* __restrict__ A,    // [20000][256] bf16
    const unsigned short* __restrict__ Bt,   // [Npad][256] bf16 (plain)
    int Ncols, int ldC,
    const float* __restrict__ bias,          // per-col bias or null
    const float* __restrict__ res,           // [M][256] fp32 residual (LN only) or null
    const float* __restrict__ g, const float* __restrict__ b,  // LN params or null
    float* __restrict__ outf, unsigned short* __restrict__ outb) {
    __shared__ unsigned short As[2][16 * 256];   // 2 x 8 KB A strip, chunk-swizzled
    __shared__ float red[8][16][2];              // per-wave (sum,sumsq) per row
    int tid = threadIdx.x, lane = tid & 63, wave = tid >> 6;
    int nl = lane & 15, quad = lane >> 4;
    int cbase = blockIdx.y * 256 + wave * 32;
    int sr = tid >> 5, sc = tid & 31;            // staging coords (row, chunk)
    int swz = (sc ^ (sr & 7)) << 3;              // swizzled ushort offset
    int R = gridDim.x;

    // B slice -> registers (once per block; each wave owns 32 distinct cols)
    bf16x8 breg[2][8];
    const unsigned short* bptr = Bt + (size_t)(cbase + nl) * 256 + quad * 8;
#pragma unroll
    for (int j = 0; j < 2; j++)
#pragma unroll
        for (int kb = 0; kb < 8; kb++)
            breg[j][kb] = *(const bf16x8*)(bptr + j * 16 * 256 + kb * 32);

    // prologue: stage strip blockIdx.x into As[0]
    int s = blockIdx.x;
    {
        ushort8 v = *(const ushort8*)(A + ((size_t)s * 16 + sr) * 256 + sc * 8);
        *(ushort8*)(&As[0][sr * 256 + swz]) = v;
    }
    __syncthreads();
    int p = 0;
    while (s < 1250) {
        int snext = s + R;
        bool more = (snext < 1250);
        ushort8 av;
        if (more)  // issue next strip's load early; latency hides under compute
            av = *(const ushort8*)(A + ((size_t)snext * 16 + sr) * 256 + sc * 8);

        floatx4 acc0 = {0.f, 0.f, 0.f, 0.f};
        floatx4 acc1 = {0.f, 0.f, 0.f, 0.f};
#pragma unroll
        for (int kb = 0; kb < 8; kb++) {
            int kq = kb * 4 + quad;
            bf16x8 a = *(const bf16x8*)(&As[p][nl * 256 + (((kq ^ (nl & 7))) << 3)]);
            acc0 = __builtin_amdgcn_mfma_f32_16x16x32_bf16(a, breg[0][kb], acc0, 0, 0, 0);
            acc1 = __builtin_amdgcn_mfma_f32_16x16x32_bf16(a, breg[1][kb], acc1, 0, 0, 0);
        }
        int row0 = s * 16;

        if (g == nullptr) {
            // plain epilogue: optional bias, col-guarded stores (rows exact)
#pragma unroll
            for (int j = 0; j < 2; j++) {
                int col = cbase + j * 16 + nl;
                if (col < Ncols) {
                    float bv = bias ? bias[col] : 0.f;
                    floatx4 aj = j ? acc1 : acc0;
#pragma unroll
                    for (int r = 0; r < 4; r++) {
                        int rr = row0 + quad * 4 + r;
                        float v = aj[r] + bv;
                        if (outf) outf[(size_t)rr * ldC + col] = v;
                        if (outb) outb[(size_t)rr * ldC + col] = f2b(v);
                    }
                }
            }
        } else {
            // fused LayerNorm epilogue (Ncols == 256, ldC == 256)
            if (res) {
#pragma unroll
                for (int r = 0; r < 4; r++) {
                    int rr = row0 + quad * 4 + r;
                    acc0[r] += res[(size_t)rr * 256 + cbase + nl];
                    acc1[r] += res[(size_t)rr * 256 + cbase + 16 + nl];
                }
            }
#pragma unroll
            for (int r = 0; r < 4; r++) {
                float su = acc0[r] + acc1[r];
                float q = fmaf(acc0[r], acc0[r], acc1[r] * acc1[r]);
                su += __shfl_xor(su, 1, 64); q += __shfl_xor(q, 1, 64);
                su += __shfl_xor(su, 2, 64); q += __shfl_xor(q, 2, 64);
                su += __shfl_xor(su, 4, 64); q += __shfl_xor(q, 4, 64);
                su += __shfl_xor(su, 8, 64); q += __shfl_xor(q, 8, 64);
                if (nl == 0) {
                    red[wave][quad * 4 + r][0] = su;
                    red[wave][quad * 4 + r][1] = q;
                }
            }
            __syncthreads();
            float mean_[4], rstd_[4];
#pragma unroll
            for (int r = 0; r < 4; r++) {
                int row = quad * 4 + r;
                float su = 0.f, q = 0.f;
#pragma unroll
                for (int w = 0; w < 8; w++) { su += red[w][row][0]; q += red[w][row][1]; }
                float mean = su * (1.0f / 256.0f);
                float var = q * (1.0f / 256.0f) - mean * mean;
                mean_[r] = mean;
                rstd_[r] = 1.0f / sqrtf(var + 1e-5f);
            }
#pragma unroll
            for (int j = 0; j < 2; j++) {
                int col = cbase + j * 16 + nl;
                float gv = g[col], bvv = b[col];
                floatx4 aj = j ? acc1 : acc0;
#pragma unroll
                for (int r = 0; r < 4; r++) {
                    int rr = row0 + quad * 4 + r;
                    float o = (aj[r] - mean_[r]) * rstd_[r] * gv + bvv;
                    if (outf) outf[(size_t)rr * 256 + col] = o;
                    if (outb) outb[(size_t)rr * 256 + col] = f2b(o);
                }
            }
        }

        if (more) *(ushort8*)(&As[p ^ 1][sr * 256 + swz]) = av;
        __syncthreads();
        p ^= 1;
        s = snext;
    }
}

// ---- CSR build: fast single-block scan (1024 threads, 20 elems/thread) ----
__global__ __launch_bounds__(1024) void k_scan(const int* __restrict__ cnt,
                                               int* __restrict__ rowptr,
                                               int* __restrict__ wp, int n) {
    __shared__ int tsum[1024];
    int t = threadIdx.x;
    const int chunk = 20;  // 1024*20 = 20480 >= 20000
    int i0 = t * chunk;
    int local[chunk];
    int s = 0;
#pragma unroll
    for (int j = 0; j < chunk; j++) {
        int i = i0 + j;
        int v = (i < n) ? cnt[i] : 0;
        local[j] = s;  // exclusive prefix within chunk
        s += v;
    }
    tsum[t] = s;
    __syncthreads();
    // inclusive Hillis-Steele scan over 1024 partials
    for (int off = 1; off < 1024; off <<= 1) {
        int other = (t >= off) ? tsum[t - off] : 0;
        __syncthreads();
        tsum[t] += other;
        __syncthreads();
    }
    int base = (t > 0) ? tsum[t - 1] : 0;
#pragma unroll
    for (int j = 0; j < chunk; j++) {
        int i = i0 + j;
        if (i < n) {
            int ex = base + local[j];
            rowptr[i] = ex;
            wp[i] = ex;
        }
    }
    if (t == 1023) rowptr[n] = tsum[1023];
}

// ---- CSR build: scatter src id + edge attr into CSR order ----
__global__ void k_fill(const int* __restrict__ src, const int* __restrict__ dst,
                       const float* __restrict__ ea, int* __restrict__ wp,
                       int* __restrict__ srcs, float* __restrict__ eas) {
    int e = blockIdx.x * blockDim.x + threadIdx.x;
    if (e >= N_EDGES) return;
    int p = atomicAdd(wp + dst[e], 1);
    srcs[p] = src[e];
    eas[p] = ea[e];
}

// ---- fused GATv2 edge phase + LayerNorm epilogue
// wave per dst node, online softmax, 2 edges/iteration.
// Edge metadata (srcs/eas) is CSR-ordered -> sequential loads, no indirection.
// Row gathers are kept 3 pairs (6 edges) in flight to cover LLC/HBM latency.
// xlr: [N][512] bf16 where cols 0..255 = x@Wl, 256..511 = x@Wr
// epilogue: o = agg + vbias (+res) ; LN(o; g,b) -> outf (fp32) / outb (bf16)
__global__ __launch_bounds__(256) void k_gat_ln(
    const int* __restrict__ rowptr, const int* __restrict__ srcs,
    const float* __restrict__ eas, const unsigned short* __restrict__ xlr,
    const float* __restrict__ We, const float* __restrict__ att,
    const float* __restrict__ vbias, const float* __restrict__ res,
    const float* __restrict__ g, const float* __restrict__ b,
    float* __restrict__ outf, unsigned short* __restrict__ outb) {
    int node = blockIdx.x * 4 + (threadIdx.x >> 6);
    if (node >= N_NODES) return;
    int lane = threadIdx.x & 63;  // lane covers dims [4*lane, 4*lane+4)
    int beg = rowptr[node], end = rowptr[node + 1];
    float4 wv = ((const float4*)We)[lane];
    float4 av = ((const float4*)att)[lane];
    ushort4 xru = ((const ushort4*)(xlr + (size_t)node * 512 + 256))[lane];
    float4 rv = make_float4(b2f(xru.x), b2f(xru.y), b2f(xru.z), b2f(xru.w));
    float m = -3.0e38f, l = 0.f;
    float4 acc = make_float4(0.f, 0.f, 0.f, 0.f);
    if (beg < end) {
        int last = end - 1;
        int i1 = (beg + 1 < end) ? beg + 1 : last;
        int i2 = (beg + 2 < end) ? beg + 2 : last;
        int i3 = (beg + 3 < end) ? beg + 3 : last;
        int i4 = (beg + 4 < end) ? beg + 4 : last;
        int i5 = (beg + 5 < end) ? beg + 5 : last;
        int i6 = (beg + 6 < end) ? beg + 6 : last;
        int i7 = (beg + 7 < end) ? beg + 7 : last;
        int s0a = srcs[beg], s0b = srcs[i1];
        int s1a = srcs[i2],  s1b = srcs[i3];
        int s2a = srcs[i4],  s2b = srcs[i5];
        int s3a = srcs[i6],  s3b = srcs[i7];
        float a0a = eas[beg], a0b = eas[i1];
        float a1a = eas[i2],  a1b = eas[i3];
        float a2a = eas[i4],  a2b = eas[i5];
        float a3a = eas[i6],  a3b = eas[i7];
        ushort4 x0a = ((const ushort4*)(xlr + (size_t)s0a * 512))[lane];
        ushort4 x0b = ((const ushort4*)(xlr + (size_t)s0b * 512))[lane];
        ushort4 x1a = ((const ushort4*)(xlr + (size_t)s1a * 512))[lane];
        ushort4 x1b = ((const ushort4*)(xlr + (size_t)s1b * 512))[lane];
        ushort4 x2a = ((const ushort4*)(xlr + (size_t)s2a * 512))[lane];
        ushort4 x2b = ((const ushort4*)(xlr + (size_t)s2b * 512))[lane];
        for (int i = beg; i < end; i += 2) {
            int j8 = (i + 8 < end) ? i + 8 : last;
            int j9 = (i + 9 < end) ? i + 9 : last;
            int s4a = srcs[j8], s4b = srcs[j9];
            float a4a = eas[j8], a4b = eas[j9];
            ushort4 x3a = ((const ushort4*)(xlr + (size_t)s3a * 512))[lane];
            ushort4 x3b = ((const ushort4*)(xlr + (size_t)s3b * 512))[lane];
            float4 lva = make_float4(b2f(x0a.x), b2f(x0a.y), b2f(x0a.z), b2f(x0a.w));
            float4 lvb = make_float4(b2f(x0b.x), b2f(x0b.y), b2f(x0b.z), b2f(x0b.w));
            float f, pa = 0.f, pb = 0.f;
            f = lva.x + rv.x + a0a * wv.x; f = fmaxf(f, 0.2f * f); pa = fmaf(f, av.x, pa);
            f = lva.y + rv.y + a0a * wv.y; f = fmaxf(f, 0.2f * f); pa = fmaf(f, av.y, pa);
            f = lva.z + rv.z + a0a * wv.z; f = fmaxf(f, 0.2f * f); pa = fmaf(f, av.z, pa);
            f = lva.w + rv.w + a0a * wv.w; f = fmaxf(f, 0.2f * f); pa = fmaf(f, av.w, pa);
            f = lvb.x + rv.x + a0b * wv.x; f = fmaxf(f, 0.2f * f); pb = fmaf(f, av.x, pb);
            f = lvb.y + rv.y + a0b * wv.y; f = fmaxf(f, 0.2f * f); pb = fmaf(f, av.y, pb);
            f = lvb.z + rv.z + a0b * wv.z; f = fmaxf(f, 0.2f * f); pb = fmaf(f, av.z, pb);
            f = lvb.w + rv.w + a0b * wv.w; f = fmaxf(f, 0.2f * f); pb = fmaf(f, av.w, pb);
            pa += __shfl_xor(pa, 1, 64);
            pa += __shfl_xor(pa, 2, 64);
            pa += __shfl_xor(pa, 4, 64);
            pb += __shfl_xor(pb, 1, 64);
            pb += __shfl_xor(pb, 2, 64);
            pb += __shfl_xor(pb, 4, 64);
            if (i + 1 >= end) pb = -3.0e38f;  // odd tail: second edge is a dummy
            float mnew = fmaxf(fmaxf(m, pa), pb);
            float scale = __expf(m - mnew);
            float wa = __expf(pa - mnew);
            float wb = __expf(pb - mnew);
            acc.x = fmaf(acc.x, scale, fmaf(wa, lva.x, wb * lvb.x));
            acc.y = fmaf(acc.y, scale, fmaf(wa, lva.y, wb * lvb.y));
            acc.z = fmaf(acc.z, scale, fmaf(wa, lva.z, wb * lvb.z));
            acc.w = fmaf(acc.w, scale, fmaf(wa, lva.w, wb * lvb.w));
            l = fmaf(l, scale, wa + wb);
            m = mnew;
            x0a = x1a; x0b = x1b; x1a = x2a; x1b = x2b; x2a = x3a; x2b = x3b;
            a0a = a1a; a0b = a1b; a1a = a2a; a1b = a2b; a2a = a3a; a2b = a3b;
            a3a = a4a; a3b = a4b; s3a = s4a; s3b = s4b;
        }
    }
    float inv = 1.0f / (l + 1e-16f);
    float4 vb4 = ((const float4*)vbias)[lane];
    float4 o = make_float4(fmaf(acc.x, inv, vb4.x), fmaf(acc.y, inv, vb4.y),
                           fmaf(acc.z, inv, vb4.z), fmaf(acc.w, inv, vb4.w));
    if (res) {
        float4 r4 = ((const float4*)(res + (size_t)node * 256))[lane];
        o.x += r4.x; o.y += r4.y; o.z += r4.z; o.w += r4.w;
    }
    float sum = o.x + o.y + o.z + o.w;
#pragma unroll
    for (int off = 32; off > 0; off >>= 1) sum += __shfl_xor(sum, off, 64);
    float mean = sum * (1.0f / 256.0f);
    float dx = o.x - mean, dy = o.y - mean, dz = o.z - mean, dw = o.w - mean;
    float sq = dx * dx + dy * dy + dz * dz + dw * dw;
#pragma unroll
    for (int off = 32; off > 0; off >>= 1) sq += __shfl_xor(sq, off, 64);
    float rstd = 1.0f / sqrtf(sq * (1.0f / 256.0f) + 1e-5f);
    float4 gg = ((const float4*)g)[lane];
    float4 bb = ((const float4*)b)[lane];
    float4 o4 = make_float4(dx * rstd * gg.x + bb.x, dy * rstd * gg.y + bb.y,
                            dz * rstd * gg.z + bb.z, dw * rstd * gg.w + bb.w);
    if (outf) ((float4*)(outf + (size_t)node * 256))[lane] = o4;
    if (outb) {
        ushort4 u;
        u.x = f2b(o4.x); u.y = f2b(o4.y); u.z = f2b(o4.z); u.w = f2b(o4.w);
        ((ushort4*)(outb + (size_t)node * 256))[lane] = u;
    }
}

extern "C" void kernel_launch(void* const* d_in, const int* in_sizes, int n_in,
                              void* d_out, int out_size, void* d_ws, size_t ws_size,
                              hipStream_t stream) {
    const float* x_gnn = (const float*)d_in[0];
    const int* ei = (const int*)d_in[1];
    const int* src = ei;
    const int* dst = ei + N_EDGES;
    const float* ea   = (const float*)d_in[2];
    const float* W_in = (const float*)d_in[3];
    const float* b_in = (const float*)d_in[4];
    const float* Wl1  = (const float*)d_in[5];
    const float* Wr1  = (const float*)d_in[6];
    const float* We1  = (const float*)d_in[7];
    const float* att1 = (const float*)d_in[8];
    const float* bg1  = (const float*)d_in[9];
    const float* ln1_g = (const float*)d_in[10];
    const float* ln1_b = (const float*)d_in[11];
    const float* W_down = (const float*)d_in[12];
    const float* lnd_g = (const float*)d_in[13];
    const float* lnd_b = (const float*)d_in[14];
    const float* Wl2  = (const float*)d_in[15];
    const float* Wr2  = (const float*)d_in[16];
    const float* We2  = (const float*)d_in[17];
    const float* att2 = (const float*)d_in[18];
    const float* bg2  = (const float*)d_in[19];
    const float* ln2_g = (const float*)d_in[20];
    const float* ln2_b = (const float*)d_in[21];
    const float* W_up = (const float*)d_in[22];
    const float* lnu_g = (const float*)d_in[23];
    const float* lnu_b = (const float*)d_in[24];
    const float* W_cls = (const float*)d_in[25];
    const float* b_cls = (const float*)d_in[26];

    // ---- workspace layout ----
    float* ws = (float*)d_ws;
    float* B_agg = ws;                                // 5,120,000 f (unused, kept for layout)
    float* B_h1  = B_agg + 5120000;                   // 5,120,000 f
    float* B_z   = B_h1 + 5120000;                    // 5,120,000 f
    unsigned short* B_xlr = (unsigned short*)(B_z + 5120000);  // 10,240,000 us ([N][512])
    unsigned short* B_actb = B_xlr + 10240000;                 // 5,120,000 us
    unsigned short* B_h0b = B_actb + 5120000;                  // 640,000 us
    unsigned short* Wt_l1 = B_h0b + 640000;                    // 8,192  ([512][32] with Wt_r1)
    unsigned short* Wt_r1 = Wt_l1 + 8192;                      // 8,192
    unsigned short* Wt_down = Wt_r1 + 8192;                    // 65,536 (plain [256][256])
    unsigned short* Wt_l2 = Wt_down + 65536;                   // ([512][256] with Wt_r2)
    unsigned short* Wt_r2 = Wt_l2 + 65536;
    unsigned short* Wt_up = Wt_r2 + 65536;                     // 65,536
    unsigned short* Wt_cls = Wt_up + 65536;                    // 262,144 ([1024][256], pad)
    int* C_cnt = (int*)(Wt_cls + 262144);                      // 20,000
    int* C_row = C_cnt + 20000;                                // 20,001
    int* C_wp  = C_row + 20001;                                // 20,000
    int* C_src = C_wp + 20000;                                 // 320,000 (CSR-ordered src)
    float* C_ea = (float*)(C_src + 320000);                    // 320,000 (CSR-ordered ea)

    float* out_logits = (float*)d_out;
    float* out_h = out_logits + (size_t)N_NODES * 1000;

    int gatblk = (N_NODES + 3) / 4;
    dim3 gl((N_NODES + 127) / 128, 4);   // K=32 gemm, N=512 (merged xl|xr)

    // 0. prep (in_proj + dst histogram + weight converts) — one launch
    hipMemsetAsync(C_cnt, 0, (size_t)20000 * 4, stream);
    k_prep<<<5862, 256, 0, stream>>>(x_gnn, W_in, b_in, B_h0b, dst, C_cnt,
                                     Wl1, Wr1, W_down, Wl2, Wr2, W_up, W_cls,
                                     Wt_l1, Wt_r1, Wt_down, Wt_l2, Wt_r2, Wt_up, Wt_cls);
    // 0b. CSR over dst (reused by both GAT layers)
    k_scan<<<1, 1024, 0, stream>>>(C_cnt, C_row, C_wp, N_NODES);
    k_fill<<<(N_EDGES + 255) / 256, 256, 0, stream>>>(src, dst, ea, C_wp, C_src, C_ea);

    // 1. merged xl|xr = h0 @ [Wl1|Wr1]  (N=512, K=32 MFMA, bf16 out)
    k_gemm_bf16<<<gl, 256, 0, stream>>>(B_h0b, Wt_l1, nullptr, B_xlr, nullptr, N_NODES, 512, 32);
    // 2. GAT1 fused (+bias +LN) -> h1 (fp32 for residual) + bf16 act
    k_gat_ln<<<gatblk, 256, 0, stream>>>(C_row, C_src, C_ea, B_xlr, We1, att1,
                                         bg1, nullptr, ln1_g, ln1_b, B_h1, B_actb);
    // 3. z = LN(h1 @ W_down)  (stride GEMM, fused LN, in-place row-safe)
    k_gemm_stride<<<dim3(512, 1), 512, 0, stream>>>(
        B_actb, Wt_down, 256, 256, nullptr, nullptr, lnd_g, lnd_b, B_z, B_actb);
    // 4. merged xl2|xr2 = z @ [Wl2|Wr2] (N=512)
    k_gemm_stride<<<dim3(256, 2), 512, 0, stream>>>(
        B_actb, Wt_l2, 512, 512, nullptr, nullptr, nullptr, nullptr, nullptr, B_xlr);
    // 5. GAT2 fused (+bias +residual z +LN) -> bf16 act
    k_gat_ln<<<gatblk, 256, 0, stream>>>(C_row, C_src, C_ea, B_xlr, We2, att2,
                                         bg2, B_z, ln2_g, ln2_b, nullptr, B_actb);
    // 6. h = LN(z2 @ W_up + h1) -> out_h (fp32) + bf16 act
    k_gemm_stride<<<dim3(512, 1), 512, 0, stream>>>(
        B_actb, Wt_up, 256, 256, nullptr, B_h1, lnu_g, lnu_b, out_h, B_actb);
    // 7. logits = h @ W_cls + b_cls  (N=1000, padded B image to 1024)
    k_gemm_stride<<<dim3(128, 4), 512, 0, stream>>>(
        B_actb, Wt_cls, 1000, 1000, b_cls, nullptr, nullptr, nullptr,
        out_logits, nullptr);
}

// Round 8
// 402.144 us; speedup vs baseline: 1.1890x; 1.0007x over previous
//
#include <hip/hip_runtime.h>
#include <math.h>

#define N_NODES 20000
#define N_EDGES 320000

typedef __attribute__((ext_vector_type(8))) __bf16 bf16x8;
typedef __attribute__((ext_vector_type(8))) unsigned short ushort8;
typedef __attribute__((ext_vector_type(4))) float floatx4;

// ---- fp32 -> bf16 (RNE) raw bits ----
__device__ __forceinline__ unsigned short f2b(float f) {
    unsigned int u = __float_as_uint(f);
    unsigned int r = (u + 0x7fffu + ((u >> 16) & 1u)) >> 16;
    return (unsigned short)r;
}
// ---- bf16 bits -> fp32 ----
__device__ __forceinline__ float b2f(unsigned short u) {
    return __uint_as_float(((unsigned int)u) << 16);
}

// ---- merged prep: in_proj + dst-histogram + all weight converts (plain) ----
//   [0, 640000)          : h0[n][p] = x[n]@W_in + b_in  (bf16)
//   [640000, 960000)     : atomicAdd histogram of dst
//   [960000, 1500672)    : W[K][N] fp32 -> Wt[N][K] bf16 (W_cls padded to 1024 rows)
__global__ void k_prep(const float* __restrict__ x, const float* __restrict__ Wi,
                       const float* __restrict__ bi, unsigned short* __restrict__ h0,
                       const int* __restrict__ dst, int* __restrict__ cnt,
                       const float* __restrict__ Wl1, const float* __restrict__ Wr1,
                       const float* __restrict__ Wdn, const float* __restrict__ Wl2,
                       const float* __restrict__ Wr2, const float* __restrict__ Wup,
                       const float* __restrict__ Wcl,
                       unsigned short* __restrict__ o1, unsigned short* __restrict__ o2,
                       unsigned short* __restrict__ o3, unsigned short* __restrict__ o4,
                       unsigned short* __restrict__ o5, unsigned short* __restrict__ o6,
                       unsigned short* __restrict__ o7) {
    int t = blockIdx.x * blockDim.x + threadIdx.x;
    if (t < 640000) {
        int n = t >> 5, p = t & 31;
        float acc = bi[p];
        const float* xr = x + n * 18;
#pragma unroll
        for (int k = 0; k < 18; k++) acc = fmaf(xr[k], Wi[k * 32 + p], acc);
        h0[t] = f2b(acc);
        return;
    }
    if (t < 960000) {
        atomicAdd(cnt + dst[t - 640000], 1);
        return;
    }
    int u = t - 960000;
    const float* W; unsigned short* O; int Nd, K, idx;
    if (u < 8192)        { W = Wl1; O = o1; Nd = 256;  K = 32;  idx = u; }
    else if (u < 16384)  { W = Wr1; O = o2; Nd = 256;  K = 32;  idx = u - 8192; }
    else if (u < 81920)  { W = Wdn; O = o3; Nd = 256;  K = 256; idx = u - 16384; }
    else if (u < 147456) { W = Wl2; O = o4; Nd = 256;  K = 256; idx = u - 81920; }
    else if (u < 212992) { W = Wr2; O = o5; Nd = 256;  K = 256; idx = u - 147456; }
    else if (u < 278528) { W = Wup; O = o6; Nd = 256;  K = 256; idx = u - 212992; }
    else if (u < 540672) { W = Wcl; O = o7; Nd = 1000; K = 256; idx = u - 278528; }
    else return;
    int n = idx / K, k = idx % K;
    float v = (n < Nd) ? W[(size_t)k * Nd + n] : 0.f;   // pad rows -> 0
    O[idx] = f2b(v);
}

// ---- bf16 MFMA GEMM (generic, LDS-staged): C[M,N] = A[M,K] @ Bt[N,K]^T
// kept only for the K=32 in-proj GEMM.
__global__ __launch_bounds__(256) void k_gemm_bf16(
    const unsigned short* __restrict__ A, const unsigned short* __restrict__ Bt,
    float* __restrict__ Cf, unsigned short* __restrict__ Cb,
    const float* __restrict__ bias, int M, int N, int K) {
    __shared__ unsigned short As[8 * 64 * 8];
    __shared__ unsigned short Bs[8 * 64 * 8];
    int tid = threadIdx.x;
    int wave = tid >> 6, lane = tid & 63;
    int wr = wave >> 1, wc = wave & 1;
    int row0 = blockIdx.x * 128, col0 = blockIdx.y * 128;
    floatx4 zero4 = {0.f, 0.f, 0.f, 0.f};
    floatx4 acc[4][4];
#pragma unroll
    for (int i = 0; i < 4; i++)
#pragma unroll
        for (int j = 0; j < 4; j++) acc[i][j] = zero4;
    for (int kb = 0; kb < K; kb += 32) {
#pragma unroll
        for (int q = 0; q < 2; q++) {
            int c = tid * 2 + q;           // 0..511
            int row = c >> 2, koff = (c & 3) * 8;
            int lp = (row & 15) + 16 * (koff >> 3);
            int mt = row >> 4;
            ushort8 va = {0, 0, 0, 0, 0, 0, 0, 0};
            if (row0 + row < M)
                va = *(const ushort8*)(A + (size_t)(row0 + row) * K + kb + koff);
            *(ushort8*)(As + (mt * 64 + lp) * 8) = va;
            ushort8 vb = {0, 0, 0, 0, 0, 0, 0, 0};
            if (col0 + row < N)
                vb = *(const ushort8*)(Bt + (size_t)(col0 + row) * K + kb + koff);
            *(ushort8*)(Bs + (mt * 64 + lp) * 8) = vb;
        }
        __syncthreads();
        bf16x8 af[4], bfr[4];
#pragma unroll
        for (int i = 0; i < 4; i++)
            af[i] = *(const bf16x8*)(As + ((wr * 4 + i) * 64 + lane) * 8);
#pragma unroll
        for (int j = 0; j < 4; j++)
            bfr[j] = *(const bf16x8*)(Bs + ((wc * 4 + j) * 64 + lane) * 8);
#pragma unroll
        for (int i = 0; i < 4; i++)
#pragma unroll
            for (int j = 0; j < 4; j++)
                acc[i][j] = __builtin_amdgcn_mfma_f32_16x16x32_bf16(
                    af[i], bfr[j], acc[i][j], 0, 0, 0);
        __syncthreads();
    }
    int quad = lane >> 4, nl = lane & 15;
#pragma unroll
    for (int i = 0; i < 4; i++) {
#pragma unroll
        for (int j = 0; j < 4; j++) {
            int col = col0 + wc * 64 + j * 16 + nl;
            if (col >= N) continue;
            float bv = bias ? bias[col] : 0.f;
#pragma unroll
            for (int r = 0; r < 4; r++) {
                int rr = row0 + wr * 64 + i * 16 + quad * 4 + r;
                if (rr >= M) continue;
                float v = acc[i][j][r] + bv;
                if (Cf) Cf[(size_t)rr * N + col] = v;
                else Cb[(size_t)rr * N + col] = f2b(v);
            }
        }
    }
}

// ---- K=256 GEMM: B in registers, grid-stride row strips, LDS-dbuf A ----
// Each block loads its B slice ONCE into registers (breg[2][8], 32 cols/wave)
// and loops row strips s = bIdx.x, s += gridDim.x. Per strip: issue next
// A-strip global load early (reg), compute current strip from LDS, store C,
// ds_write next strip, one barrier. B traffic = #blocks * 128 KB.
__global__ __launch_bounds__(512) void k_gemm_stride(
    const unsigned short* __restrict__ A,    // [20000][256] bf16
    const unsigned short* __restrict__ Bt,   // [Npad][256] bf16 (plain)
    int Ncols, int ldC,
    const float* __restrict__ bias,          // per-col bias or null
    const float* __restrict__ res,           // [M][256] fp32 residual (LN only) or null
    const float* __restrict__ g, const float* __restrict__ b,  // LN params or null
    float* __restrict__ outf, unsigned short* __restrict__ outb) {
    __shared__ unsigned short As[2][16 * 256];   // 2 x 8 KB A strip, chunk-swizzled
    __shared__ float red[8][16][2];              // per-wave (sum,sumsq) per row
    int tid = threadIdx.x, lane = tid & 63, wave = tid >> 6;
    int nl = lane & 15, quad = lane >> 4;
    int cbase = blockIdx.y * 256 + wave * 32;
    int sr = tid >> 5, sc = tid & 31;            // staging coords (row, chunk)
    int swz = (sc ^ (sr & 7)) << 3;              // swizzled ushort offset
    int R = gridDim.x;

    // B slice -> registers (once per block; each wave owns 32 distinct cols)
    bf16x8 breg[2][8];
    const unsigned short* bptr = Bt + (size_t)(cbase + nl) * 256 + quad * 8;
#pragma unroll
    for (int j = 0; j < 2; j++)
#pragma unroll
        for (int kb = 0; kb < 8; kb++)
            breg[j][kb] = *(const bf16x8*)(bptr + j * 16 * 256 + kb * 32);

    // prologue: stage strip blockIdx.x into As[0]
    int s = blockIdx.x;
    {
        ushort8 v = *(const ushort8*)(A + ((size_t)s * 16 + sr) * 256 + sc * 8);
        *(ushort8*)(&As[0][sr * 256 + swz]) = v;
    }
    __syncthreads();
    int p = 0;
    while (s < 1250) {
        int snext = s + R;
        bool more = (snext < 1250);
        ushort8 av;
        if (more)  // issue next strip's load early; latency hides under compute
            av = *(const ushort8*)(A + ((size_t)snext * 16 + sr) * 256 + sc * 8);

        floatx4 acc0 = {0.f, 0.f, 0.f, 0.f};
        floatx4 acc1 = {0.f, 0.f, 0.f, 0.f};
#pragma unroll
        for (int kb = 0; kb < 8; kb++) {
            int kq = kb * 4 + quad;
            bf16x8 a = *(const bf16x8*)(&As[p][nl * 256 + (((kq ^ (nl & 7))) << 3)]);
            acc0 = __builtin_amdgcn_mfma_f32_16x16x32_bf16(a, breg[0][kb], acc0, 0, 0, 0);
            acc1 = __builtin_amdgcn_mfma_f32_16x16x32_bf16(a, breg[1][kb], acc1, 0, 0, 0);
        }
        int row0 = s * 16;

        if (g == nullptr) {
            // plain epilogue: optional bias, col-guarded stores (rows exact)
#pragma unroll
            for (int j = 0; j < 2; j++) {
                int col = cbase + j * 16 + nl;
                if (col < Ncols) {
                    float bv = bias ? bias[col] : 0.f;
                    floatx4 aj = j ? acc1 : acc0;
#pragma unroll
                    for (int r = 0; r < 4; r++) {
                        int rr = row0 + quad * 4 + r;
                        float v = aj[r] + bv;
                        if (outf) outf[(size_t)rr * ldC + col] = v;
                        if (outb) outb[(size_t)rr * ldC + col] = f2b(v);
                    }
                }
            }
        } else {
            // fused LayerNorm epilogue (Ncols == 256, ldC == 256)
            if (res) {
#pragma unroll
                for (int r = 0; r < 4; r++) {
                    int rr = row0 + quad * 4 + r;
                    acc0[r] += res[(size_t)rr * 256 + cbase + nl];
                    acc1[r] += res[(size_t)rr * 256 + cbase + 16 + nl];
                }
            }
#pragma unroll
            for (int r = 0; r < 4; r++) {
                float su = acc0[r] + acc1[r];
                float q = fmaf(acc0[r], acc0[r], acc1[r] * acc1[r]);
                su += __shfl_xor(su, 1, 64); q += __shfl_xor(q, 1, 64);
                su += __shfl_xor(su, 2, 64); q += __shfl_xor(q, 2, 64);
                su += __shfl_xor(su, 4, 64); q += __shfl_xor(q, 4, 64);
                su += __shfl_xor(su, 8, 64); q += __shfl_xor(q, 8, 64);
                if (nl == 0) {
                    red[wave][quad * 4 + r][0] = su;
                    red[wave][quad * 4 + r][1] = q;
                }
            }
            __syncthreads();
            float mean_[4], rstd_[4];
#pragma unroll
            for (int r = 0; r < 4; r++) {
                int row = quad * 4 + r;
                float su = 0.f, q = 0.f;
#pragma unroll
                for (int w = 0; w < 8; w++) { su += red[w][row][0]; q += red[w][row][1]; }
                float mean = su * (1.0f / 256.0f);
                float var = q * (1.0f / 256.0f) - mean * mean;
                mean_[r] = mean;
                rstd_[r] = 1.0f / sqrtf(var + 1e-5f);
            }
#pragma unroll
            for (int j = 0; j < 2; j++) {
                int col = cbase + j * 16 + nl;
                float gv = g[col], bvv = b[col];
                floatx4 aj = j ? acc1 : acc0;
#pragma unroll
                for (int r = 0; r < 4; r++) {
                    int rr = row0 + quad * 4 + r;
                    float o = (aj[r] - mean_[r]) * rstd_[r] * gv + bvv;
                    if (outf) outf[(size_t)rr * 256 + col] = o;
                    if (outb) outb[(size_t)rr * 256 + col] = f2b(o);
                }
            }
        }

        if (more) *(ushort8*)(&As[p ^ 1][sr * 256 + swz]) = av;
        __syncthreads();
        p ^= 1;
        s = snext;
    }
}

// ---- CSR build: fast single-block scan (1024 threads, 20 elems/thread) ----
__global__ __launch_bounds__(1024) void k_scan(const int* __restrict__ cnt,
                                               int* __restrict__ rowptr,
                                               int* __restrict__ wp, int n) {
    __shared__ int tsum[1024];
    int t = threadIdx.x;
    const int chunk = 20;  // 1024*20 = 20480 >= 20000
    int i0 = t * chunk;
    int local[chunk];
    int s = 0;
#pragma unroll
    for (int j = 0; j < chunk; j++) {
        int i = i0 + j;
        int v = (i < n) ? cnt[i] : 0;
        local[j] = s;  // exclusive prefix within chunk
        s += v;
    }
    tsum[t] = s;
    __syncthreads();
    // inclusive Hillis-Steele scan over 1024 partials
    for (int off = 1; off < 1024; off <<= 1) {
        int other = (t >= off) ? tsum[t - off] : 0;
        __syncthreads();
        tsum[t] += other;
        __syncthreads();
    }
    int base = (t > 0) ? tsum[t - 1] : 0;
#pragma unroll
    for (int j = 0; j < chunk; j++) {
        int i = i0 + j;
        if (i < n) {
            int ex = base + local[j];
            rowptr[i] = ex;
            wp[i] = ex;
        }
    }
    if (t == 1023) rowptr[n] = tsum[1023];
}

// ---- CSR build: scatter src id + edge attr into CSR order ----
__global__ void k_fill(const int* __restrict__ src, const int* __restrict__ dst,
                       const float* __restrict__ ea, int* __restrict__ wp,
                       int* __restrict__ srcs, float* __restrict__ eas) {
    int e = blockIdx.x * blockDim.x + threadIdx.x;
    if (e >= N_EDGES) return;
    int p = atomicAdd(wp + dst[e], 1);
    srcs[p] = src[e];
    eas[p] = ea[e];
}

// ---- fused GATv2 edge phase + LayerNorm epilogue
// wave per dst node, online softmax, 2 edges/iteration.
// Edge metadata (srcs/eas) is CSR-ordered -> sequential loads, no indirection.
// v2: row-gather pipeline deepened to 5 pairs (10 edges in flight); the issue
// point for a row is 4 loop bodies (~450-500 cy) before its use, covering the
// ~600 cy LLC latency that round-7 counters showed as ~58% stall.
// xlr: [N][512] bf16 where cols 0..255 = x@Wl, 256..511 = x@Wr
// epilogue: o = agg + vbias (+res) ; LN(o; g,b) -> outf (fp32) / outb (bf16)
__global__ __launch_bounds__(256) void k_gat_ln(
    const int* __restrict__ rowptr, const int* __restrict__ srcs,
    const float* __restrict__ eas, const unsigned short* __restrict__ xlr,
    const float* __restrict__ We, const float* __restrict__ att,
    const float* __restrict__ vbias, const float* __restrict__ res,
    const float* __restrict__ g, const float* __restrict__ b,
    float* __restrict__ outf, unsigned short* __restrict__ outb) {
    int node = blockIdx.x * 4 + (threadIdx.x >> 6);
    if (node >= N_NODES) return;
    int lane = threadIdx.x & 63;  // lane covers dims [4*lane, 4*lane+4)
    int beg = rowptr[node], end = rowptr[node + 1];
    float4 wv = ((const float4*)We)[lane];
    float4 av = ((const float4*)att)[lane];
    ushort4 xru = ((const ushort4*)(xlr + (size_t)node * 512 + 256))[lane];
    float4 rv = make_float4(b2f(xru.x), b2f(xru.y), b2f(xru.z), b2f(xru.w));
    float m = -3.0e38f, l = 0.f;
    float4 acc = make_float4(0.f, 0.f, 0.f, 0.f);
    if (beg < end) {
        int last = end - 1;
        int i1 = (beg + 1 < end) ? beg + 1 : last;
        int i2 = (beg + 2 < end) ? beg + 2 : last;
        int i3 = (beg + 3 < end) ? beg + 3 : last;
        int i4 = (beg + 4 < end) ? beg + 4 : last;
        int i5 = (beg + 5 < end) ? beg + 5 : last;
        int i6 = (beg + 6 < end) ? beg + 6 : last;
        int i7 = (beg + 7 < end) ? beg + 7 : last;
        int i8 = (beg + 8 < end) ? beg + 8 : last;
        int i9 = (beg + 9 < end) ? beg + 9 : last;
        // scalars for pairs 0..4
        int s0a = srcs[beg], s0b = srcs[i1];
        int s1a = srcs[i2],  s1b = srcs[i3];
        int s2a = srcs[i4],  s2b = srcs[i5];
        int s3a = srcs[i6],  s3b = srcs[i7];
        int s4a = srcs[i8],  s4b = srcs[i9];
        float a0a = eas[beg], a0b = eas[i1];
        float a1a = eas[i2],  a1b = eas[i3];
        float a2a = eas[i4],  a2b = eas[i5];
        float a3a = eas[i6],  a3b = eas[i7];
        float a4a = eas[i8],  a4b = eas[i9];
        // rows for pairs 0..3
        ushort4 x0a = ((const ushort4*)(xlr + (size_t)s0a * 512))[lane];
        ushort4 x0b = ((const ushort4*)(xlr + (size_t)s0b * 512))[lane];
        ushort4 x1a = ((const ushort4*)(xlr + (size_t)s1a * 512))[lane];
        ushort4 x1b = ((const ushort4*)(xlr + (size_t)s1b * 512))[lane];
        ushort4 x2a = ((const ushort4*)(xlr + (size_t)s2a * 512))[lane];
        ushort4 x2b = ((const ushort4*)(xlr + (size_t)s2b * 512))[lane];
        ushort4 x3a = ((const ushort4*)(xlr + (size_t)s3a * 512))[lane];
        ushort4 x3b = ((const ushort4*)(xlr + (size_t)s3b * 512))[lane];
        for (int i = beg; i < end; i += 2) {
            // stage scalars for pair 5 (streaming, no indirection)
            int j10 = (i + 10 < end) ? i + 10 : last;
            int j11 = (i + 11 < end) ? i + 11 : last;
            int s5a = srcs[j10], s5b = srcs[j11];
            float a5a = eas[j10], a5b = eas[j11];
            // issue rows for pair 4 (used 4 iterations from now)
            ushort4 x4a = ((const ushort4*)(xlr + (size_t)s4a * 512))[lane];
            ushort4 x4b = ((const ushort4*)(xlr + (size_t)s4b * 512))[lane];
            // compute with pair0: (x0a, a0a), (x0b, a0b)
            float4 lva = make_float4(b2f(x0a.x), b2f(x0a.y), b2f(x0a.z), b2f(x0a.w));
            float4 lvb = make_float4(b2f(x0b.x), b2f(x0b.y), b2f(x0b.z), b2f(x0b.w));
            float f, pa = 0.f, pb = 0.f;
            f = lva.x + rv.x + a0a * wv.x; f = fmaxf(f, 0.2f * f); pa = fmaf(f, av.x, pa);
            f = lva.y + rv.y + a0a * wv.y; f = fmaxf(f, 0.2f * f); pa = fmaf(f, av.y, pa);
            f = lva.z + rv.z + a0a * wv.z; f = fmaxf(f, 0.2f * f); pa = fmaf(f, av.z, pa);
            f = lva.w + rv.w + a0a * wv.w; f = fmaxf(f, 0.2f * f); pa = fmaf(f, av.w, pa);
            f = lvb.x + rv.x + a0b * wv.x; f = fmaxf(f, 0.2f * f); pb = fmaf(f, av.x, pb);
            f = lvb.y + rv.y + a0b * wv.y; f = fmaxf(f, 0.2f * f); pb = fmaf(f, av.y, pb);
            f = lvb.z + rv.z + a0b * wv.z; f = fmaxf(f, 0.2f * f); pb = fmaf(f, av.z, pb);
            f = lvb.w + rv.w + a0b * wv.w; f = fmaxf(f, 0.2f * f); pb = fmaf(f, av.w, pb);
            // per-head (8-lane group) score reduction
            pa += __shfl_xor(pa, 1, 64);
            pa += __shfl_xor(pa, 2, 64);
            pa += __shfl_xor(pa, 4, 64);
            pb += __shfl_xor(pb, 1, 64);
            pb += __shfl_xor(pb, 2, 64);
            pb += __shfl_xor(pb, 4, 64);
            if (i + 1 >= end) pb = -3.0e38f;  // odd tail: second edge is a dummy
            float mnew = fmaxf(fmaxf(m, pa), pb);
            float scale = __expf(m - mnew);
            float wa = __expf(pa - mnew);
            float wb = __expf(pb - mnew);
            acc.x = fmaf(acc.x, scale, fmaf(wa, lva.x, wb * lvb.x));
            acc.y = fmaf(acc.y, scale, fmaf(wa, lva.y, wb * lvb.y));
            acc.z = fmaf(acc.z, scale, fmaf(wa, lva.z, wb * lvb.z));
            acc.w = fmaf(acc.w, scale, fmaf(wa, lva.w, wb * lvb.w));
            l = fmaf(l, scale, wa + wb);
            m = mnew;
            // shift pipeline
            x0a = x1a; x0b = x1b; x1a = x2a; x1b = x2b;
            x2a = x3a; x2b = x3b; x3a = x4a; x3b = x4b;
            a0a = a1a; a0b = a1b; a1a = a2a; a1b = a2b;
            a2a = a3a; a2b = a3b; a3a = a4a; a3b = a4b;
            a4a = a5a; a4b = a5b; s4a = s5a; s4b = s5b;
        }
    }
    float inv = 1.0f / (l + 1e-16f);
    float4 vb4 = ((const float4*)vbias)[lane];
    float4 o = make_float4(fmaf(acc.x, inv, vb4.x), fmaf(acc.y, inv, vb4.y),
                           fmaf(acc.z, inv, vb4.z), fmaf(acc.w, inv, vb4.w));
    if (res) {
        float4 r4 = ((const float4*)(res + (size_t)node * 256))[lane];
        o.x += r4.x; o.y += r4.y; o.z += r4.z; o.w += r4.w;
    }
    float sum = o.x + o.y + o.z + o.w;
#pragma unroll
    for (int off = 32; off > 0; off >>= 1) sum += __shfl_xor(sum, off, 64);
    float mean = sum * (1.0f / 256.0f);
    float dx = o.x - mean, dy = o.y - mean, dz = o.z - mean, dw = o.w - mean;
    float sq = dx * dx + dy * dy + dz * dz + dw * dw;
#pragma unroll
    for (int off = 32; off > 0; off >>= 1) sq += __shfl_xor(sq, off, 64);
    float rstd = 1.0f / sqrtf(sq * (1.0f / 256.0f) + 1e-5f);
    float4 gg = ((const float4*)g)[lane];
    float4 bb = ((const float4*)b)[lane];
    float4 o4 = make_float4(dx * rstd * gg.x + bb.x, dy * rstd * gg.y + bb.y,
                            dz * rstd * gg.z + bb.z, dw * rstd * gg.w + bb.w);
    if (outf) ((float4*)(outf + (size_t)node * 256))[lane] = o4;
    if (outb) {
        ushort4 u;
        u.x = f2b(o4.x); u.y = f2b(o4.y); u.z = f2b(o4.z); u.w = f2b(o4.w);
        ((ushort4*)(outb + (size_t)node * 256))[lane] = u;
    }
}

extern "C" void kernel_launch(void* const* d_in, const int* in_sizes, int n_in,
                              void* d_out, int out_size, void* d_ws, size_t ws_size,
                              hipStream_t stream) {
    const float* x_gnn = (const float*)d_in[0];
    const int* ei = (const int*)d_in[1];
    const int* src = ei;
    const int* dst = ei + N_EDGES;
    const float* ea   = (const float*)d_in[2];
    const float* W_in = (const float*)d_in[3];
    const float* b_in = (const float*)d_in[4];
    const float* Wl1  = (const float*)d_in[5];
    const float* Wr1  = (const float*)d_in[6];
    const float* We1  = (const float*)d_in[7];
    const float* att1 = (const float*)d_in[8];
    const float* bg1  = (const float*)d_in[9];
    const float* ln1_g = (const float*)d_in[10];
    const float* ln1_b = (const float*)d_in[11];
    const float* W_down = (const float*)d_in[12];
    const float* lnd_g = (const float*)d_in[13];
    const float* lnd_b = (const float*)d_in[14];
    const float* Wl2  = (const float*)d_in[15];
    const float* Wr2  = (const float*)d_in[16];
    const float* We2  = (const float*)d_in[17];
    const float* att2 = (const float*)d_in[18];
    const float* bg2  = (const float*)d_in[19];
    const float* ln2_g = (const float*)d_in[20];
    const float* ln2_b = (const float*)d_in[21];
    const float* W_up = (const float*)d_in[22];
    const float* lnu_g = (const float*)d_in[23];
    const float* lnu_b = (const float*)d_in[24];
    const float* W_cls = (const float*)d_in[25];
    const float* b_cls = (const float*)d_in[26];

    // ---- workspace layout ----
    float* ws = (float*)d_ws;
    float* B_agg = ws;                                // 5,120,000 f (unused, kept for layout)
    float* B_h1  = B_agg + 5120000;                   // 5,120,000 f
    float* B_z   = B_h1 + 5120000;                    // 5,120,000 f
    unsigned short* B_xlr = (unsigned short*)(B_z + 5120000);  // 10,240,000 us ([N][512])
    unsigned short* B_actb = B_xlr + 10240000;                 // 5,120,000 us
    unsigned short* B_h0b = B_actb + 5120000;                  // 640,000 us
    unsigned short* Wt_l1 = B_h0b + 640000;                    // 8,192  ([512][32] with Wt_r1)
    unsigned short* Wt_r1 = Wt_l1 + 8192;                      // 8,192
    unsigned short* Wt_down = Wt_r1 + 8192;                    // 65,536 (plain [256][256])
    unsigned short* Wt_l2 = Wt_down + 65536;                   // ([512][256] with Wt_r2)
    unsigned short* Wt_r2 = Wt_l2 + 65536;
    unsigned short* Wt_up = Wt_r2 + 65536;                     // 65,536
    unsigned short* Wt_cls = Wt_up + 65536;                    // 262,144 ([1024][256], pad)
    int* C_cnt = (int*)(Wt_cls + 262144);                      // 20,000
    int* C_row = C_cnt + 20000;                                // 20,001
    int* C_wp  = C_row + 20001;                                // 20,000
    int* C_src = C_wp + 20000;                                 // 320,000 (CSR-ordered src)
    float* C_ea = (float*)(C_src + 320000);                    // 320,000 (CSR-ordered ea)

    float* out_logits = (float*)d_out;
    float* out_h = out_logits + (size_t)N_NODES * 1000;

    int gatblk = (N_NODES + 3) / 4;
    dim3 gl((N_NODES + 127) / 128, 4);   // K=32 gemm, N=512 (merged xl|xr)

    // 0. prep (in_proj + dst histogram + weight converts) — one launch
    hipMemsetAsync(C_cnt, 0, (size_t)20000 * 4, stream);
    k_prep<<<5862, 256, 0, stream>>>(x_gnn, W_in, b_in, B_h0b, dst, C_cnt,
                                     Wl1, Wr1, W_down, Wl2, Wr2, W_up, W_cls,
                                     Wt_l1, Wt_r1, Wt_down, Wt_l2, Wt_r2, Wt_up, Wt_cls);
    // 0b. CSR over dst (reused by both GAT layers)
    k_scan<<<1, 1024, 0, stream>>>(C_cnt, C_row, C_wp, N_NODES);
    k_fill<<<(N_EDGES + 255) / 256, 256, 0, stream>>>(src, dst, ea, C_wp, C_src, C_ea);

    // 1. merged xl|xr = h0 @ [Wl1|Wr1]  (N=512, K=32 MFMA, bf16 out)
    k_gemm_bf16<<<gl, 256, 0, stream>>>(B_h0b, Wt_l1, nullptr, B_xlr, nullptr, N_NODES, 512, 32);
    // 2. GAT1 fused (+bias +LN) -> h1 (fp32 for residual) + bf16 act
    k_gat_ln<<<gatblk, 256, 0, stream>>>(C_row, C_src, C_ea, B_xlr, We1, att1,
                                         bg1, nullptr, ln1_g, ln1_b, B_h1, B_actb);
    // 3. z = LN(h1 @ W_down)  (stride GEMM, fused LN, in-place row-safe)
    k_gemm_stride<<<dim3(512, 1), 512, 0, stream>>>(
        B_actb, Wt_down, 256, 256, nullptr, nullptr, lnd_g, lnd_b, B_z, B_actb);
    // 4. merged xl2|xr2 = z @ [Wl2|Wr2] (N=512)
    k_gemm_stride<<<dim3(256, 2), 512, 0, stream>>>(
        B_actb, Wt_l2, 512, 512, nullptr, nullptr, nullptr, nullptr, nullptr, B_xlr);
    // 5. GAT2 fused (+bias +residual z +LN) -> bf16 act
    k_gat_ln<<<gatblk, 256, 0, stream>>>(C_row, C_src, C_ea, B_xlr, We2, att2,
                                         bg2, B_z, ln2_g, ln2_b, nullptr, B_actb);
    // 6. h = LN(z2 @ W_up + h1) -> out_h (fp32) + bf16 act
    k_gemm_stride<<<dim3(512, 1), 512, 0, stream>>>(
        B_actb, Wt_up, 256, 256, nullptr, B_h1, lnu_g, lnu_b, out_h, B_actb);
    // 7. logits = h @ W_cls + b_cls  (N=1000, padded B image to 1024)
    k_gemm_stride<<<dim3(128, 4), 512, 0, stream>>>(
        B_actb, Wt_cls, 1000, 1000, b_cls, nullptr, nullptr, nullptr,
        out_logits, nullptr);
}

// Round 9
// 395.267 us; speedup vs baseline: 1.2097x; 1.0174x over previous
//
#include <hip/hip_runtime.h>
#include <math.h>

#define N_NODES 20000
#define N_EDGES 320000

typedef __attribute__((ext_vector_type(8))) __bf16 bf16x8;
typedef __attribute__((ext_vector_type(8))) unsigned short ushort8;
typedef __attribute__((ext_vector_type(4))) float floatx4;

// ---- fp32 -> bf16 (RNE) raw bits ----
__device__ __forceinline__ unsigned short f2b(float f) {
    unsigned int u = __float_as_uint(f);
    unsigned int r = (u + 0x7fffu + ((u >> 16) & 1u)) >> 16;
    return (unsigned short)r;
}
// ---- bf16 bits -> fp32 ----
__device__ __forceinline__ float b2f(unsigned short u) {
    return __uint_as_float(((unsigned int)u) << 16);
}

// ---- merged prep: in_proj + dst-histogram + all weight converts (plain) ----
//   [0, 640000)          : h0[n][p] = x[n]@W_in + b_in  (bf16)
//   [640000, 960000)     : atomicAdd histogram of dst
//   [960000, 1500672)    : W[K][N] fp32 -> Wt[N][K] bf16 (W_cls padded to 1024 rows)
__global__ void k_prep(const float* __restrict__ x, const float* __restrict__ Wi,
                       const float* __restrict__ bi, unsigned short* __restrict__ h0,
                       const int* __restrict__ dst, int* __restrict__ cnt,
                       const float* __restrict__ Wl1, const float* __restrict__ Wr1,
                       const float* __restrict__ Wdn, const float* __restrict__ Wl2,
                       const float* __restrict__ Wr2, const float* __restrict__ Wup,
                       const float* __restrict__ Wcl,
                       unsigned short* __restrict__ o1, unsigned short* __restrict__ o2,
                       unsigned short* __restrict__ o3, unsigned short* __restrict__ o4,
                       unsigned short* __restrict__ o5, unsigned short* __restrict__ o6,
                       unsigned short* __restrict__ o7) {
    int t = blockIdx.x * blockDim.x + threadIdx.x;
    if (t < 640000) {
        int n = t >> 5, p = t & 31;
        float acc = bi[p];
        const float* xr = x + n * 18;
#pragma unroll
        for (int k = 0; k < 18; k++) acc = fmaf(xr[k], Wi[k * 32 + p], acc);
        h0[t] = f2b(acc);
        return;
    }
    if (t < 960000) {
        atomicAdd(cnt + dst[t - 640000], 1);
        return;
    }
    int u = t - 960000;
    const float* W; unsigned short* O; int Nd, K, idx;
    if (u < 8192)        { W = Wl1; O = o1; Nd = 256;  K = 32;  idx = u; }
    else if (u < 16384)  { W = Wr1; O = o2; Nd = 256;  K = 32;  idx = u - 8192; }
    else if (u < 81920)  { W = Wdn; O = o3; Nd = 256;  K = 256; idx = u - 16384; }
    else if (u < 147456) { W = Wl2; O = o4; Nd = 256;  K = 256; idx = u - 81920; }
    else if (u < 212992) { W = Wr2; O = o5; Nd = 256;  K = 256; idx = u - 147456; }
    else if (u < 278528) { W = Wup; O = o6; Nd = 256;  K = 256; idx = u - 212992; }
    else if (u < 540672) { W = Wcl; O = o7; Nd = 1000; K = 256; idx = u - 278528; }
    else return;
    int n = idx / K, k = idx % K;
    float v = (n < Nd) ? W[(size_t)k * Nd + n] : 0.f;   // pad rows -> 0
    O[idx] = f2b(v);
}

// ---- bf16 MFMA GEMM (generic, LDS-staged): C[M,N] = A[M,K] @ Bt[N,K]^T
// kept only for the K=32 in-proj GEMM.
__global__ __launch_bounds__(256) void k_gemm_bf16(
    const unsigned short* __restrict__ A, const unsigned short* __restrict__ Bt,
    float* __restrict__ Cf, unsigned short* __restrict__ Cb,
    const float* __restrict__ bias, int M, int N, int K) {
    __shared__ unsigned short As[8 * 64 * 8];
    __shared__ unsigned short Bs[8 * 64 * 8];
    int tid = threadIdx.x;
    int wave = tid >> 6, lane = tid & 63;
    int wr = wave >> 1, wc = wave & 1;
    int row0 = blockIdx.x * 128, col0 = blockIdx.y * 128;
    floatx4 zero4 = {0.f, 0.f, 0.f, 0.f};
    floatx4 acc[4][4];
#pragma unroll
    for (int i = 0; i < 4; i++)
#pragma unroll
        for (int j = 0; j < 4; j++) acc[i][j] = zero4;
    for (int kb = 0; kb < K; kb += 32) {
#pragma unroll
        for (int q = 0; q < 2; q++) {
            int c = tid * 2 + q;           // 0..511
            int row = c >> 2, koff = (c & 3) * 8;
            int lp = (row & 15) + 16 * (koff >> 3);
            int mt = row >> 4;
            ushort8 va = {0, 0, 0, 0, 0, 0, 0, 0};
            if (row0 + row < M)
                va = *(const ushort8*)(A + (size_t)(row0 + row) * K + kb + koff);
            *(ushort8*)(As + (mt * 64 + lp) * 8) = va;
            ushort8 vb = {0, 0, 0, 0, 0, 0, 0, 0};
            if (col0 + row < N)
                vb = *(const ushort8*)(Bt + (size_t)(col0 + row) * K + kb + koff);
            *(ushort8*)(Bs + (mt * 64 + lp) * 8) = vb;
        }
        __syncthreads();
        bf16x8 af[4], bfr[4];
#pragma unroll
        for (int i = 0; i < 4; i++)
            af[i] = *(const bf16x8*)(As + ((wr * 4 + i) * 64 + lane) * 8);
#pragma unroll
        for (int j = 0; j < 4; j++)
            bfr[j] = *(const bf16x8*)(Bs + ((wc * 4 + j) * 64 + lane) * 8);
#pragma unroll
        for (int i = 0; i < 4; i++)
#pragma unroll
            for (int j = 0; j < 4; j++)
                acc[i][j] = __builtin_amdgcn_mfma_f32_16x16x32_bf16(
                    af[i], bfr[j], acc[i][j], 0, 0, 0);
        __syncthreads();
    }
    int quad = lane >> 4, nl = lane & 15;
#pragma unroll
    for (int i = 0; i < 4; i++) {
#pragma unroll
        for (int j = 0; j < 4; j++) {
            int col = col0 + wc * 64 + j * 16 + nl;
            if (col >= N) continue;
            float bv = bias ? bias[col] : 0.f;
#pragma unroll
            for (int r = 0; r < 4; r++) {
                int rr = row0 + wr * 64 + i * 16 + quad * 4 + r;
                if (rr >= M) continue;
                float v = acc[i][j][r] + bv;
                if (Cf) Cf[(size_t)rr * N + col] = v;
                else Cb[(size_t)rr * N + col] = f2b(v);
            }
        }
    }
}

// ---- K=256 GEMM: B in registers, grid-stride row strips, LDS-dbuf A ----
// Each block loads its B slice ONCE into registers (breg[2][8], 32 cols/wave)
// and loops row strips s = bIdx.x, s += gridDim.x (strips are exclusively
// owned by one block -> in-place A/outb is race-free).
// res (residual, LN path) is bf16 now.
__global__ __launch_bounds__(512) void k_gemm_stride(
    const unsigned short* __restrict__ A,    // [20000][256] bf16
    const unsigned short* __restrict__ Bt,   // [Npad][256] bf16 (plain)
    int Ncols, int ldC,
    const float* __restrict__ bias,          // per-col bias or null
    const unsigned short* __restrict__ res,  // [M][256] bf16 residual (LN only) or null
    const float* __restrict__ g, const float* __restrict__ b,  // LN params or null
    float* __restrict__ outf, unsigned short* __restrict__ outb) {
    __shared__ unsigned short As[2][16 * 256];   // 2 x 8 KB A strip, chunk-swizzled
    __shared__ float red[8][16][2];              // per-wave (sum,sumsq) per row
    int tid = threadIdx.x, lane = tid & 63, wave = tid >> 6;
    int nl = lane & 15, quad = lane >> 4;
    int cbase = blockIdx.y * 256 + wave * 32;
    int sr = tid >> 5, sc = tid & 31;            // staging coords (row, chunk)
    int swz = (sc ^ (sr & 7)) << 3;              // swizzled ushort offset
    int R = gridDim.x;

    // B slice -> registers (once per block; each wave owns 32 distinct cols)
    bf16x8 breg[2][8];
    const unsigned short* bptr = Bt + (size_t)(cbase + nl) * 256 + quad * 8;
#pragma unroll
    for (int j = 0; j < 2; j++)
#pragma unroll
        for (int kb = 0; kb < 8; kb++)
            breg[j][kb] = *(const bf16x8*)(bptr + j * 16 * 256 + kb * 32);

    // prologue: stage strip blockIdx.x into As[0]
    int s = blockIdx.x;
    {
        ushort8 v = *(const ushort8*)(A + ((size_t)s * 16 + sr) * 256 + sc * 8);
        *(ushort8*)(&As[0][sr * 256 + swz]) = v;
    }
    __syncthreads();
    int p = 0;
    while (s < 1250) {
        int snext = s + R;
        bool more = (snext < 1250);
        ushort8 av;
        if (more)  // issue next strip's load early; latency hides under compute
            av = *(const ushort8*)(A + ((size_t)snext * 16 + sr) * 256 + sc * 8);

        floatx4 acc0 = {0.f, 0.f, 0.f, 0.f};
        floatx4 acc1 = {0.f, 0.f, 0.f, 0.f};
#pragma unroll
        for (int kb = 0; kb < 8; kb++) {
            int kq = kb * 4 + quad;
            bf16x8 a = *(const bf16x8*)(&As[p][nl * 256 + (((kq ^ (nl & 7))) << 3)]);
            acc0 = __builtin_amdgcn_mfma_f32_16x16x32_bf16(a, breg[0][kb], acc0, 0, 0, 0);
            acc1 = __builtin_amdgcn_mfma_f32_16x16x32_bf16(a, breg[1][kb], acc1, 0, 0, 0);
        }
        int row0 = s * 16;

        if (g == nullptr) {
            // plain epilogue: optional bias, col-guarded stores (rows exact)
#pragma unroll
            for (int j = 0; j < 2; j++) {
                int col = cbase + j * 16 + nl;
                if (col < Ncols) {
                    float bv = bias ? bias[col] : 0.f;
                    floatx4 aj = j ? acc1 : acc0;
#pragma unroll
                    for (int r = 0; r < 4; r++) {
                        int rr = row0 + quad * 4 + r;
                        float v = aj[r] + bv;
                        if (outf) outf[(size_t)rr * ldC + col] = v;
                        if (outb) outb[(size_t)rr * ldC + col] = f2b(v);
                    }
                }
            }
        } else {
            // fused LayerNorm epilogue (Ncols == 256, ldC == 256)
            if (res) {
#pragma unroll
                for (int r = 0; r < 4; r++) {
                    int rr = row0 + quad * 4 + r;
                    acc0[r] += b2f(res[(size_t)rr * 256 + cbase + nl]);
                    acc1[r] += b2f(res[(size_t)rr * 256 + cbase + 16 + nl]);
                }
            }
#pragma unroll
            for (int r = 0; r < 4; r++) {
                float su = acc0[r] + acc1[r];
                float q = fmaf(acc0[r], acc0[r], acc1[r] * acc1[r]);
                su += __shfl_xor(su, 1, 64); q += __shfl_xor(q, 1, 64);
                su += __shfl_xor(su, 2, 64); q += __shfl_xor(q, 2, 64);
                su += __shfl_xor(su, 4, 64); q += __shfl_xor(q, 4, 64);
                su += __shfl_xor(su, 8, 64); q += __shfl_xor(q, 8, 64);
                if (nl == 0) {
                    red[wave][quad * 4 + r][0] = su;
                    red[wave][quad * 4 + r][1] = q;
                }
            }
            __syncthreads();
            float mean_[4], rstd_[4];
#pragma unroll
            for (int r = 0; r < 4; r++) {
                int row = quad * 4 + r;
                float su = 0.f, q = 0.f;
#pragma unroll
                for (int w = 0; w < 8; w++) { su += red[w][row][0]; q += red[w][row][1]; }
                float mean = su * (1.0f / 256.0f);
                float var = q * (1.0f / 256.0f) - mean * mean;
                mean_[r] = mean;
                rstd_[r] = 1.0f / sqrtf(var + 1e-5f);
            }
#pragma unroll
            for (int j = 0; j < 2; j++) {
                int col = cbase + j * 16 + nl;
                float gv = g[col], bvv = b[col];
                floatx4 aj = j ? acc1 : acc0;
#pragma unroll
                for (int r = 0; r < 4; r++) {
                    int rr = row0 + quad * 4 + r;
                    float o = (aj[r] - mean_[r]) * rstd_[r] * gv + bvv;
                    if (outf) outf[(size_t)rr * 256 + col] = o;
                    if (outb) outb[(size_t)rr * 256 + col] = f2b(o);
                }
            }
        }

        if (more) *(ushort8*)(&As[p ^ 1][sr * 256 + swz]) = av;
        __syncthreads();
        p ^= 1;
        s = snext;
    }
}

// ---- fused bottleneck: z = LN(h1 @ W_down) ; xlr2 = z @ [Wl2|Wr2] ----
// Row-local chain -> one kernel. 512 threads, 8 waves; B1 (W_down, 32 cols/wave)
// and B2 (Wl2 or Wr2 half per blockIdx.y, 32 cols/wave) live in registers across
// 10 strips (grid.x = 125, strips s, s+125, ...). z goes through swizzled LDS
// (GEMM2's A operand) and bf16 to global (GAT2 residual, y==0 only).
// GEMM1 is duplicated across the two y-blocks (16 MFMAs/strip - negligible).
__global__ __launch_bounds__(512) void k_fuse(
    const unsigned short* __restrict__ A,      // h1b [20000][256] bf16
    const unsigned short* __restrict__ Bdn,    // Wt_down [256][256] bf16
    const unsigned short* __restrict__ B2base, // Wt_l2 ([512][256] with Wt_r2)
    const float* __restrict__ g, const float* __restrict__ b,   // lnd params
    unsigned short* __restrict__ zb,           // [20000][256] bf16 (y==0 writes)
    unsigned short* __restrict__ xlr) {        // [20000][512] bf16
    __shared__ unsigned short As[2][16 * 256];
    __shared__ unsigned short Zs[16 * 256];
    __shared__ float red[8][16][2];
    int tid = threadIdx.x, lane = tid & 63, wave = tid >> 6;
    int nl = lane & 15, quad = lane >> 4;
    int sr = tid >> 5, sc = tid & 31;
    int swz = (sc ^ (sr & 7)) << 3;
    int ybase = blockIdx.y * 256;
    const unsigned short* B2 = B2base + (size_t)blockIdx.y * 65536;

    // B1: 32 cols/wave of W_down
    bf16x8 b1[2][8];
    const unsigned short* p1 = Bdn + (size_t)(wave * 32 + nl) * 256 + quad * 8;
#pragma unroll
    for (int j = 0; j < 2; j++)
#pragma unroll
        for (int kb = 0; kb < 8; kb++)
            b1[j][kb] = *(const bf16x8*)(p1 + j * 16 * 256 + kb * 32);
    // B2: 32 cols/wave of this block's [Wl2|Wr2] half
    bf16x8 b2[2][8];
    const unsigned short* p2 = B2 + (size_t)(wave * 32 + nl) * 256 + quad * 8;
#pragma unroll
    for (int j = 0; j < 2; j++)
#pragma unroll
        for (int kb = 0; kb < 8; kb++)
            b2[j][kb] = *(const bf16x8*)(p2 + j * 16 * 256 + kb * 32);

    int s = blockIdx.x;   // strips s, s+125, ... (1250 = 125 * 10)
    {
        ushort8 v = *(const ushort8*)(A + ((size_t)s * 16 + sr) * 256 + sc * 8);
        *(ushort8*)(&As[0][sr * 256 + swz]) = v;
    }
    __syncthreads();
    int p = 0;
    while (s < 1250) {
        int snext = s + 125;
        bool more = (snext < 1250);
        ushort8 av;
        if (more)
            av = *(const ushort8*)(A + ((size_t)snext * 16 + sr) * 256 + sc * 8);

        // GEMM1: h1_strip @ W_down
        floatx4 acc0 = {0.f, 0.f, 0.f, 0.f};
        floatx4 acc1 = {0.f, 0.f, 0.f, 0.f};
#pragma unroll
        for (int kb = 0; kb < 8; kb++) {
            int kq = kb * 4 + quad;
            bf16x8 a = *(const bf16x8*)(&As[p][nl * 256 + ((kq ^ (nl & 7)) << 3)]);
            acc0 = __builtin_amdgcn_mfma_f32_16x16x32_bf16(a, b1[0][kb], acc0, 0, 0, 0);
            acc1 = __builtin_amdgcn_mfma_f32_16x16x32_bf16(a, b1[1][kb], acc1, 0, 0, 0);
        }
        int row0 = s * 16;
        // LN over 256 cols (cross-wave)
#pragma unroll
        for (int r = 0; r < 4; r++) {
            float su = acc0[r] + acc1[r];
            float q = fmaf(acc0[r], acc0[r], acc1[r] * acc1[r]);
            su += __shfl_xor(su, 1, 64); q += __shfl_xor(q, 1, 64);
            su += __shfl_xor(su, 2, 64); q += __shfl_xor(q, 2, 64);
            su += __shfl_xor(su, 4, 64); q += __shfl_xor(q, 4, 64);
            su += __shfl_xor(su, 8, 64); q += __shfl_xor(q, 8, 64);
            if (nl == 0) {
                red[wave][quad * 4 + r][0] = su;
                red[wave][quad * 4 + r][1] = q;
            }
        }
        __syncthreads();
        float mean_[4], rstd_[4];
#pragma unroll
        for (int r = 0; r < 4; r++) {
            int row = quad * 4 + r;
            float su = 0.f, q = 0.f;
#pragma unroll
            for (int w = 0; w < 8; w++) { su += red[w][row][0]; q += red[w][row][1]; }
            float mean = su * (1.0f / 256.0f);
            float var = q * (1.0f / 256.0f) - mean * mean;
            mean_[r] = mean;
            rstd_[r] = 1.0f / sqrtf(var + 1e-5f);
        }
        // z -> swizzled LDS (GEMM2 A operand) + bf16 global (GAT2 residual)
#pragma unroll
        for (int j = 0; j < 2; j++) {
            int col = wave * 32 + j * 16 + nl;
            float gv = g[col], bvv = b[col];
            floatx4 aj = j ? acc1 : acc0;
#pragma unroll
            for (int r = 0; r < 4; r++) {
                int rl = quad * 4 + r;
                float zv = (aj[r] - mean_[r]) * rstd_[r] * gv + bvv;
                unsigned short us = f2b(zv);
                Zs[rl * 256 + (((col >> 3) ^ (rl & 7)) << 3) + (col & 7)] = us;
                if (blockIdx.y == 0) zb[(size_t)(row0 + rl) * 256 + col] = us;
            }
        }
        __syncthreads();
        // GEMM2: z_strip @ B2-half
        floatx4 c0 = {0.f, 0.f, 0.f, 0.f};
        floatx4 c1 = {0.f, 0.f, 0.f, 0.f};
#pragma unroll
        for (int kb = 0; kb < 8; kb++) {
            int kq = kb * 4 + quad;
            bf16x8 a = *(const bf16x8*)(&Zs[nl * 256 + ((kq ^ (nl & 7)) << 3)]);
            c0 = __builtin_amdgcn_mfma_f32_16x16x32_bf16(a, b2[0][kb], c0, 0, 0, 0);
            c1 = __builtin_amdgcn_mfma_f32_16x16x32_bf16(a, b2[1][kb], c1, 0, 0, 0);
        }
#pragma unroll
        for (int j = 0; j < 2; j++) {
            int col = ybase + wave * 32 + j * 16 + nl;
            floatx4 cj = j ? c1 : c0;
#pragma unroll
            for (int r = 0; r < 4; r++)
                xlr[(size_t)(row0 + quad * 4 + r) * 512 + col] = f2b(cj[r]);
        }
        if (more) *(ushort8*)(&As[p ^ 1][sr * 256 + swz]) = av;
        __syncthreads();
        p ^= 1;
        s = snext;
    }
}

// ---- CSR build: fast single-block scan (1024 threads, 20 elems/thread) ----
__global__ __launch_bounds__(1024) void k_scan(const int* __restrict__ cnt,
                                               int* __restrict__ rowptr,
                                               int* __restrict__ wp, int n) {
    __shared__ int tsum[1024];
    int t = threadIdx.x;
    const int chunk = 20;  // 1024*20 = 20480 >= 20000
    int i0 = t * chunk;
    int local[chunk];
    int s = 0;
#pragma unroll
    for (int j = 0; j < chunk; j++) {
        int i = i0 + j;
        int v = (i < n) ? cnt[i] : 0;
        local[j] = s;  // exclusive prefix within chunk
        s += v;
    }
    tsum[t] = s;
    __syncthreads();
    // inclusive Hillis-Steele scan over 1024 partials
    for (int off = 1; off < 1024; off <<= 1) {
        int other = (t >= off) ? tsum[t - off] : 0;
        __syncthreads();
        tsum[t] += other;
        __syncthreads();
    }
    int base = (t > 0) ? tsum[t - 1] : 0;
#pragma unroll
    for (int j = 0; j < chunk; j++) {
        int i = i0 + j;
        if (i < n) {
            int ex = base + local[j];
            rowptr[i] = ex;
            wp[i] = ex;
        }
    }
    if (t == 1023) rowptr[n] = tsum[1023];
}

// ---- CSR build: scatter src id + edge attr into CSR order ----
__global__ void k_fill(const int* __restrict__ src, const int* __restrict__ dst,
                       const float* __restrict__ ea, int* __restrict__ wp,
                       int* __restrict__ srcs, float* __restrict__ eas) {
    int e = blockIdx.x * blockDim.x + threadIdx.x;
    if (e >= N_EDGES) return;
    int p = atomicAdd(wp + dst[e], 1);
    srcs[p] = src[e];
    eas[p] = ea[e];
}

// ---- fused GATv2 edge phase + LayerNorm epilogue
// wave per dst node, online softmax, 2 edges/iteration, 5-pair pipeline.
// res (residual) is bf16 now.
__global__ __launch_bounds__(256) void k_gat_ln(
    const int* __restrict__ rowptr, const int* __restrict__ srcs,
    const float* __restrict__ eas, const unsigned short* __restrict__ xlr,
    const float* __restrict__ We, const float* __restrict__ att,
    const float* __restrict__ vbias, const unsigned short* __restrict__ res,
    const float* __restrict__ g, const float* __restrict__ b,
    float* __restrict__ outf, unsigned short* __restrict__ outb) {
    int node = blockIdx.x * 4 + (threadIdx.x >> 6);
    if (node >= N_NODES) return;
    int lane = threadIdx.x & 63;  // lane covers dims [4*lane, 4*lane+4)
    int beg = rowptr[node], end = rowptr[node + 1];
    float4 wv = ((const float4*)We)[lane];
    float4 av = ((const float4*)att)[lane];
    ushort4 xru = ((const ushort4*)(xlr + (size_t)node * 512 + 256))[lane];
    float4 rv = make_float4(b2f(xru.x), b2f(xru.y), b2f(xru.z), b2f(xru.w));
    float m = -3.0e38f, l = 0.f;
    float4 acc = make_float4(0.f, 0.f, 0.f, 0.f);
    if (beg < end) {
        int last = end - 1;
        int i1 = (beg + 1 < end) ? beg + 1 : last;
        int i2 = (beg + 2 < end) ? beg + 2 : last;
        int i3 = (beg + 3 < end) ? beg + 3 : last;
        int i4 = (beg + 4 < end) ? beg + 4 : last;
        int i5 = (beg + 5 < end) ? beg + 5 : last;
        int i6 = (beg + 6 < end) ? beg + 6 : last;
        int i7 = (beg + 7 < end) ? beg + 7 : last;
        int i8 = (beg + 8 < end) ? beg + 8 : last;
        int i9 = (beg + 9 < end) ? beg + 9 : last;
        int s0a = srcs[beg], s0b = srcs[i1];
        int s1a = srcs[i2],  s1b = srcs[i3];
        int s2a = srcs[i4],  s2b = srcs[i5];
        int s3a = srcs[i6],  s3b = srcs[i7];
        int s4a = srcs[i8],  s4b = srcs[i9];
        float a0a = eas[beg], a0b = eas[i1];
        float a1a = eas[i2],  a1b = eas[i3];
        float a2a = eas[i4],  a2b = eas[i5];
        float a3a = eas[i6],  a3b = eas[i7];
        float a4a = eas[i8],  a4b = eas[i9];
        ushort4 x0a = ((const ushort4*)(xlr + (size_t)s0a * 512))[lane];
        ushort4 x0b = ((const ushort4*)(xlr + (size_t)s0b * 512))[lane];
        ushort4 x1a = ((const ushort4*)(xlr + (size_t)s1a * 512))[lane];
        ushort4 x1b = ((const ushort4*)(xlr + (size_t)s1b * 512))[lane];
        ushort4 x2a = ((const ushort4*)(xlr + (size_t)s2a * 512))[lane];
        ushort4 x2b = ((const ushort4*)(xlr + (size_t)s2b * 512))[lane];
        ushort4 x3a = ((const ushort4*)(xlr + (size_t)s3a * 512))[lane];
        ushort4 x3b = ((const ushort4*)(xlr + (size_t)s3b * 512))[lane];
        for (int i = beg; i < end; i += 2) {
            int j10 = (i + 10 < end) ? i + 10 : last;
            int j11 = (i + 11 < end) ? i + 11 : last;
            int s5a = srcs[j10], s5b = srcs[j11];
            float a5a = eas[j10], a5b = eas[j11];
            ushort4 x4a = ((const ushort4*)(xlr + (size_t)s4a * 512))[lane];
            ushort4 x4b = ((const ushort4*)(xlr + (size_t)s4b * 512))[lane];
            float4 lva = make_float4(b2f(x0a.x), b2f(x0a.y), b2f(x0a.z), b2f(x0a.w));
            float4 lvb = make_float4(b2f(x0b.x), b2f(x0b.y), b2f(x0b.z), b2f(x0b.w));
            float f, pa = 0.f, pb = 0.f;
            f = lva.x + rv.x + a0a * wv.x; f = fmaxf(f, 0.2f * f); pa = fmaf(f, av.x, pa);
            f = lva.y + rv.y + a0a * wv.y; f = fmaxf(f, 0.2f * f); pa = fmaf(f, av.y, pa);
            f = lva.z + rv.z + a0a * wv.z; f = fmaxf(f, 0.2f * f); pa = fmaf(f, av.z, pa);
            f = lva.w + rv.w + a0a * wv.w; f = fmaxf(f, 0.2f * f); pa = fmaf(f, av.w, pa);
            f = lvb.x + rv.x + a0b * wv.x; f = fmaxf(f, 0.2f * f); pb = fmaf(f, av.x, pb);
            f = lvb.y + rv.y + a0b * wv.y; f = fmaxf(f, 0.2f * f); pb = fmaf(f, av.y, pb);
            f = lvb.z + rv.z + a0b * wv.z; f = fmaxf(f, 0.2f * f); pb = fmaf(f, av.z, pb);
            f = lvb.w + rv.w + a0b * wv.w; f = fmaxf(f, 0.2f * f); pb = fmaf(f, av.w, pb);
            pa += __shfl_xor(pa, 1, 64);
            pa += __shfl_xor(pa, 2, 64);
            pa += __shfl_xor(pa, 4, 64);
            pb += __shfl_xor(pb, 1, 64);
            pb += __shfl_xor(pb, 2, 64);
            pb += __shfl_xor(pb, 4, 64);
            if (i + 1 >= end) pb = -3.0e38f;  // odd tail: second edge is a dummy
            float mnew = fmaxf(fmaxf(m, pa), pb);
            float scale = __expf(m - mnew);
            float wa = __expf(pa - mnew);
            float wb = __expf(pb - mnew);
            acc.x = fmaf(acc.x, scale, fmaf(wa, lva.x, wb * lvb.x));
            acc.y = fmaf(acc.y, scale, fmaf(wa, lva.y, wb * lvb.y));
            acc.z = fmaf(acc.z, scale, fmaf(wa, lva.z, wb * lvb.z));
            acc.w = fmaf(acc.w, scale, fmaf(wa, lva.w, wb * lvb.w));
            l = fmaf(l, scale, wa + wb);
            m = mnew;
            x0a = x1a; x0b = x1b; x1a = x2a; x1b = x2b;
            x2a = x3a; x2b = x3b; x3a = x4a; x3b = x4b;
            a0a = a1a; a0b = a1b; a1a = a2a; a1b = a2b;
            a2a = a3a; a2b = a3b; a3a = a4a; a3b = a4b;
            a4a = a5a; a4b = a5b; s4a = s5a; s4b = s5b;
        }
    }
    float inv = 1.0f / (l + 1e-16f);
    float4 vb4 = ((const float4*)vbias)[lane];
    float4 o = make_float4(fmaf(acc.x, inv, vb4.x), fmaf(acc.y, inv, vb4.y),
                           fmaf(acc.z, inv, vb4.z), fmaf(acc.w, inv, vb4.w));
    if (res) {
        ushort4 r4 = ((const ushort4*)(res + (size_t)node * 256))[lane];
        o.x += b2f(r4.x); o.y += b2f(r4.y); o.z += b2f(r4.z); o.w += b2f(r4.w);
    }
    float sum = o.x + o.y + o.z + o.w;
#pragma unroll
    for (int off = 32; off > 0; off >>= 1) sum += __shfl_xor(sum, off, 64);
    float mean = sum * (1.0f / 256.0f);
    float dx = o.x - mean, dy = o.y - mean, dz = o.z - mean, dw = o.w - mean;
    float sq = dx * dx + dy * dy + dz * dz + dw * dw;
#pragma unroll
    for (int off = 32; off > 0; off >>= 1) sq += __shfl_xor(sq, off, 64);
    float rstd = 1.0f / sqrtf(sq * (1.0f / 256.0f) + 1e-5f);
    float4 gg = ((const float4*)g)[lane];
    float4 bb = ((const float4*)b)[lane];
    float4 o4 = make_float4(dx * rstd * gg.x + bb.x, dy * rstd * gg.y + bb.y,
                            dz * rstd * gg.z + bb.z, dw * rstd * gg.w + bb.w);
    if (outf) ((float4*)(outf + (size_t)node * 256))[lane] = o4;
    if (outb) {
        ushort4 u;
        u.x = f2b(o4.x); u.y = f2b(o4.y); u.z = f2b(o4.z); u.w = f2b(o4.w);
        ((ushort4*)(outb + (size_t)node * 256))[lane] = u;
    }
}

extern "C" void kernel_launch(void* const* d_in, const int* in_sizes, int n_in,
                              void* d_out, int out_size, void* d_ws, size_t ws_size,
                              hipStream_t stream) {
    const float* x_gnn = (const float*)d_in[0];
    const int* ei = (const int*)d_in[1];
    const int* src = ei;
    const int* dst = ei + N_EDGES;
    const float* ea   = (const float*)d_in[2];
    const float* W_in = (const float*)d_in[3];
    const float* b_in = (const float*)d_in[4];
    const float* Wl1  = (const float*)d_in[5];
    const float* Wr1  = (const float*)d_in[6];
    const float* We1  = (const float*)d_in[7];
    const float* att1 = (const float*)d_in[8];
    const float* bg1  = (const float*)d_in[9];
    const float* ln1_g = (const float*)d_in[10];
    const float* ln1_b = (const float*)d_in[11];
    const float* W_down = (const float*)d_in[12];
    const float* lnd_g = (const float*)d_in[13];
    const float* lnd_b = (const float*)d_in[14];
    const float* Wl2  = (const float*)d_in[15];
    const float* Wr2  = (const float*)d_in[16];
    const float* We2  = (const float*)d_in[17];
    const float* att2 = (const float*)d_in[18];
    const float* bg2  = (const float*)d_in[19];
    const float* ln2_g = (const float*)d_in[20];
    const float* ln2_b = (const float*)d_in[21];
    const float* W_up = (const float*)d_in[22];
    const float* lnu_g = (const float*)d_in[23];
    const float* lnu_b = (const float*)d_in[24];
    const float* W_cls = (const float*)d_in[25];
    const float* b_cls = (const float*)d_in[26];

    // ---- workspace layout (bf16-centric) ----
    unsigned short* B_h1b = (unsigned short*)d_ws;             // 5,120,000 us (h1, bf16)
    unsigned short* B_zb  = B_h1b + 5120000;                   // 5,120,000 us (z, bf16)
    unsigned short* B_xlr = B_zb + 5120000;                    // 10,240,000 us ([N][512])
    unsigned short* B_actb = B_xlr + 10240000;                 // 5,120,000 us
    unsigned short* B_h0b = B_actb + 5120000;                  // 640,000 us
    unsigned short* Wt_l1 = B_h0b + 640000;                    // 8,192 ([512][32] with Wt_r1)
    unsigned short* Wt_r1 = Wt_l1 + 8192;                      // 8,192
    unsigned short* Wt_down = Wt_r1 + 8192;                    // 65,536 (plain [256][256])
    unsigned short* Wt_l2 = Wt_down + 65536;                   // ([512][256] with Wt_r2)
    unsigned short* Wt_r2 = Wt_l2 + 65536;
    unsigned short* Wt_up = Wt_r2 + 65536;                     // 65,536
    unsigned short* Wt_cls = Wt_up + 65536;                    // 262,144 ([1024][256], pad)
    int* C_cnt = (int*)(Wt_cls + 262144);                      // 20,000
    int* C_row = C_cnt + 20000;                                // 20,001
    int* C_wp  = C_row + 20001;                                // 20,000
    int* C_src = C_wp + 20000;                                 // 320,000 (CSR-ordered src)
    float* C_ea = (float*)(C_src + 320000);                    // 320,000 (CSR-ordered ea)

    float* out_logits = (float*)d_out;
    float* out_h = out_logits + (size_t)N_NODES * 1000;

    int gatblk = (N_NODES + 3) / 4;
    dim3 gl((N_NODES + 127) / 128, 4);   // K=32 gemm, N=512 (merged xl|xr)

    // 0. prep (in_proj + dst histogram + weight converts) — one launch
    hipMemsetAsync(C_cnt, 0, (size_t)20000 * 4, stream);
    k_prep<<<5862, 256, 0, stream>>>(x_gnn, W_in, b_in, B_h0b, dst, C_cnt,
                                     Wl1, Wr1, W_down, Wl2, Wr2, W_up, W_cls,
                                     Wt_l1, Wt_r1, Wt_down, Wt_l2, Wt_r2, Wt_up, Wt_cls);
    // 0b. CSR over dst (reused by both GAT layers)
    k_scan<<<1, 1024, 0, stream>>>(C_cnt, C_row, C_wp, N_NODES);
    k_fill<<<(N_EDGES + 255) / 256, 256, 0, stream>>>(src, dst, ea, C_wp, C_src, C_ea);

    // 1. merged xl|xr = h0 @ [Wl1|Wr1]  (N=512, K=32 MFMA, bf16 out)
    k_gemm_bf16<<<gl, 256, 0, stream>>>(B_h0b, Wt_l1, nullptr, B_xlr, nullptr, N_NODES, 512, 32);
    // 2. GAT1 fused (+bias +LN) -> h1 (bf16: GEMM-A for W_down AND residual for step 5)
    k_gat_ln<<<gatblk, 256, 0, stream>>>(C_row, C_src, C_ea, B_xlr, We1, att1,
                                         bg1, nullptr, ln1_g, ln1_b, nullptr, B_h1b);
    // 3. FUSED: z = LN(h1 @ W_down); xlr2 = z @ [Wl2|Wr2]  (one kernel)
    k_fuse<<<dim3(125, 2), 512, 0, stream>>>(B_h1b, Wt_down, Wt_l2,
                                             lnd_g, lnd_b, B_zb, B_xlr);
    // 4. GAT2 fused (+bias +residual z(bf16) +LN) -> bf16 act
    k_gat_ln<<<gatblk, 256, 0, stream>>>(C_row, C_src, C_ea, B_xlr, We2, att2,
                                         bg2, B_zb, ln2_g, ln2_b, nullptr, B_actb);
    // 5. h = LN(z2 @ W_up + h1(bf16)) -> out_h (fp32) + bf16 act (in-place safe)
    k_gemm_stride<<<dim3(512, 1), 512, 0, stream>>>(
        B_actb, Wt_up, 256, 256, nullptr, B_h1b, lnu_g, lnu_b, out_h, B_actb);
    // 6. logits = h @ W_cls + b_cls  (N=1000, padded B image to 1024)
    k_gemm_stride<<<dim3(128, 4), 512, 0, stream>>>(
        B_actb, Wt_cls, 1000, 1000, b_cls, nullptr, nullptr, nullptr,
        out_logits, nullptr);
}